// Round 1
// baseline (2598.188 us; speedup 1.0000x reference)
//
#include <hip/hip_runtime.h>
#include <cstdint>
#include <cstddef>

// ---------------- helpers ----------------

__device__ inline float sigmoidf_fast(float x) {
    return 1.0f / (1.0f + __expf(-x));
}

// ---------------- degree / norm ----------------

__global__ void count_deg_f(const int* __restrict__ src, const int* __restrict__ dst,
                            float* __restrict__ dout, float* __restrict__ din, int E) {
    int i = blockIdx.x * 256 + threadIdx.x;
    if (i < E) {
        atomicAdd(&dout[src[i]], 1.0f);
        atomicAdd(&din[dst[i]], 1.0f);
    }
}

__global__ void finalize_norm(float* __restrict__ x, float add, int n) {
    int i = blockIdx.x * 256 + threadIdx.x;
    if (i < n) {
        float d = x[i] + add;
        x[i] = d > 0.0f ? rsqrtf(d) : 0.0f;
    }
}

// ---------------- CSR build ----------------

__global__ void count_int(const int* __restrict__ dst, int* __restrict__ cnt, int E) {
    int i = blockIdx.x * 256 + threadIdx.x;
    if (i < E) atomicAdd(&cnt[dst[i]], 1);
}

__global__ void scan_kernel(const int* __restrict__ counts, int* __restrict__ rowptr, int n) {
    __shared__ int partial[1024];
    int tid = threadIdx.x;
    int per = (n + 1023) >> 10;
    int start = tid * per;
    int s = 0;
    for (int i = 0; i < per; ++i) {
        int idx = start + i;
        if (idx < n) s += counts[idx];
    }
    partial[tid] = s;
    __syncthreads();
    for (int off = 1; off < 1024; off <<= 1) {
        int v = (tid >= off) ? partial[tid - off] : 0;
        __syncthreads();
        partial[tid] += v;
        __syncthreads();
    }
    int run = (tid > 0) ? partial[tid - 1] : 0;
    for (int i = 0; i < per; ++i) {
        int idx = start + i;
        if (idx < n) { rowptr[idx] = run; run += counts[idx]; }
    }
    if (tid == 1023) rowptr[n] = partial[1023];
}

__global__ void scatter_csr(const int* __restrict__ src, const int* __restrict__ dst,
                            const int* __restrict__ rowptr, int* __restrict__ cursor,
                            int* __restrict__ colout, int E) {
    int i = blockIdx.x * 256 + threadIdx.x;
    if (i < E) {
        int d = dst[i];
        int pos = atomicAdd(&cursor[d], 1);
        colout[rowptr[d] + pos] = src[i];
    }
}

// ---------------- generic fp32 GEMM: C = act((A@B)*scale + bias) [+C] ----------------
// A [M,K] row-major, B [K,NC] row-major, C [M,NC]. 64x64 tile, 256 threads, 4x4/thread.
// Requires K%16==0, NC%64==0. M arbitrary (row guards).

__global__ __launch_bounds__(256) void gemm_kernel(
    const float* __restrict__ A, const float* __restrict__ B,
    const float* __restrict__ scale, const float* __restrict__ bias,
    float* __restrict__ C, int M, int K, int NC, int accumulate)
{
    __shared__ float As[16][64];
    __shared__ float Bs[16][64];
    int tid = threadIdx.x;
    int tx = tid & 15, ty = tid >> 4;
    int rowBase = blockIdx.y * 64;
    int colBase = blockIdx.x * 64;

    int lm  = tid >> 2;          // A-tile row 0..63
    int lkq = (tid & 3) << 2;    // A-tile k quad 0,4,8,12
    int lk  = tid >> 4;          // B-tile k 0..15
    int lnq = (tid & 15) << 2;   // B-tile col quad

    int arow = rowBase + lm;
    if (arow >= M) arow = M - 1;

    float acc[4][4] = {};

    for (int k0 = 0; k0 < K; k0 += 16) {
        float4 av = *(const float4*)(A + (size_t)arow * K + (k0 + lkq));
        float4 bv = *(const float4*)(B + (size_t)(k0 + lk) * NC + colBase + lnq);
        As[lkq + 0][lm] = av.x;
        As[lkq + 1][lm] = av.y;
        As[lkq + 2][lm] = av.z;
        As[lkq + 3][lm] = av.w;
        *(float4*)&Bs[lk][lnq] = bv;
        __syncthreads();
#pragma unroll
        for (int k = 0; k < 16; ++k) {
            float4 a = *(const float4*)&As[k][ty << 2];
            float4 b = *(const float4*)&Bs[k][tx << 2];
            acc[0][0] += a.x * b.x; acc[0][1] += a.x * b.y; acc[0][2] += a.x * b.z; acc[0][3] += a.x * b.w;
            acc[1][0] += a.y * b.x; acc[1][1] += a.y * b.y; acc[1][2] += a.y * b.z; acc[1][3] += a.y * b.w;
            acc[2][0] += a.z * b.x; acc[2][1] += a.z * b.y; acc[2][2] += a.z * b.z; acc[2][3] += a.z * b.w;
            acc[3][0] += a.w * b.x; acc[3][1] += a.w * b.y; acc[3][2] += a.w * b.z; acc[3][3] += a.w * b.w;
        }
        __syncthreads();
    }

    int c = colBase + (tx << 2);
#pragma unroll
    for (int i = 0; i < 4; ++i) {
        int r = rowBase + (ty << 2) + i;
        if (r >= M) continue;
        float s = scale ? scale[r] : 1.0f;
        float4 o;
        o.x = acc[i][0] * s; o.y = acc[i][1] * s; o.z = acc[i][2] * s; o.w = acc[i][3] * s;
        if (bias) { o.x += bias[c]; o.y += bias[c + 1]; o.z += bias[c + 2]; o.w += bias[c + 3]; }
        float* cp = C + (size_t)r * NC + c;
        if (accumulate) {
            float4 old = *(const float4*)cp;
            o.x += old.x; o.y += old.y; o.z += old.z; o.w += old.w;
        }
        *(float4*)cp = o;
    }
}

// ---------------- fused gather SpMM + epilogue ----------------
// out[r,:] = act((sum_{e: dst=e->r} h[src_e,:] + (SELF? selfh[r,:] : 0)) * n_in[r] + bias)

template<int W, int RELU, int SELF>
__global__ __launch_bounds__(256) void spmm_fused(
    const int* __restrict__ rowptr, const int* __restrict__ col,
    const float* __restrict__ h, const float* __restrict__ selfh,
    const float* __restrict__ n_in, const float* __restrict__ bias,
    float* __restrict__ out, int M)
{
    constexpr int TPR = W / 4;       // threads per row (float4 lanes)
    constexpr int RPB = 256 / TPR;   // rows per block
    int lane = threadIdx.x & (TPR - 1);
    int r = blockIdx.x * RPB + (threadIdx.x / TPR);
    if (r >= M) return;
    int c = lane << 2;

    float4 acc = make_float4(0.f, 0.f, 0.f, 0.f);
    int beg = rowptr[r], end = rowptr[r + 1];
    for (int j = beg; j < end; ++j) {
        int s = col[j];
        float4 v = *(const float4*)(h + (size_t)s * W + c);
        acc.x += v.x; acc.y += v.y; acc.z += v.z; acc.w += v.w;
    }
    if (SELF) {
        float4 v = *(const float4*)(selfh + (size_t)r * W + c);
        acc.x += v.x; acc.y += v.y; acc.z += v.z; acc.w += v.w;
    }
    float ni = n_in[r];
    float4 b = *(const float4*)(bias + c);
    float4 o;
    o.x = acc.x * ni + b.x;
    o.y = acc.y * ni + b.y;
    o.z = acc.z * ni + b.z;
    o.w = acc.w * ni + b.w;
    if (RELU) {
        o.x = fmaxf(o.x, 0.f); o.y = fmaxf(o.y, 0.f);
        o.z = fmaxf(o.z, 0.f); o.w = fmaxf(o.w, 0.f);
    }
    *(float4*)(out + (size_t)r * W + c) = o;
}

// ---------------- decoder: out[r,c] = sigmoid(dot(Z[r,:],X[c,:])), K=128, 3 copies ----------------

__global__ __launch_bounds__(256) void adj_kernel(
    const float* __restrict__ Z, const float* __restrict__ X,
    float* __restrict__ out, int M)
{
    __shared__ float Zs[128][64];
    __shared__ float Xs[128][64];
    int tid = threadIdx.x;
    int tx = tid & 15, ty = tid >> 4;
    int rowBase = blockIdx.y * 64, colBase = blockIdx.x * 64;

    for (int it = 0; it < 8; ++it) {
        int idx = tid + (it << 8);      // 0..2047
        int m = idx >> 5;               // 0..63
        int k4 = (idx & 31) << 2;       // 0..124
        int zr = rowBase + m; if (zr >= M) zr = M - 1;
        float4 v = *(const float4*)(Z + (size_t)zr * 128 + k4);
        Zs[k4 + 0][m] = v.x; Zs[k4 + 1][m] = v.y; Zs[k4 + 2][m] = v.z; Zs[k4 + 3][m] = v.w;
        int xr = colBase + m; if (xr >= M) xr = M - 1;
        float4 w = *(const float4*)(X + (size_t)xr * 128 + k4);
        Xs[k4 + 0][m] = w.x; Xs[k4 + 1][m] = w.y; Xs[k4 + 2][m] = w.z; Xs[k4 + 3][m] = w.w;
    }
    __syncthreads();

    float acc[4][4] = {};
#pragma unroll 8
    for (int k = 0; k < 128; ++k) {
        float4 a = *(const float4*)&Zs[k][ty << 2];
        float4 b = *(const float4*)&Xs[k][tx << 2];
        acc[0][0] += a.x * b.x; acc[0][1] += a.x * b.y; acc[0][2] += a.x * b.z; acc[0][3] += a.x * b.w;
        acc[1][0] += a.y * b.x; acc[1][1] += a.y * b.y; acc[1][2] += a.y * b.z; acc[1][3] += a.y * b.w;
        acc[2][0] += a.z * b.x; acc[2][1] += a.z * b.y; acc[2][2] += a.z * b.z; acc[2][3] += a.z * b.w;
        acc[3][0] += a.w * b.x; acc[3][1] += a.w * b.y; acc[3][2] += a.w * b.z; acc[3][3] += a.w * b.w;
    }

    size_t NN = (size_t)M * M;
    int c = colBase + (tx << 2);
    if (c < M) {
#pragma unroll
        for (int i = 0; i < 4; ++i) {
            int r = rowBase + (ty << 2) + i;
            if (r >= M) continue;
            float4 o;
            o.x = sigmoidf_fast(acc[i][0]);
            o.y = sigmoidf_fast(acc[i][1]);
            o.z = sigmoidf_fast(acc[i][2]);
            o.w = sigmoidf_fast(acc[i][3]);
            float* p = out + (size_t)r * M + c;
            *(float4*)p = o;
            *(float4*)(p + NN) = o;
            *(float4*)(p + 2 * NN) = o;
        }
    }
}

// ---------------- launcher ----------------

extern "C" void kernel_launch(void* const* d_in, const int* in_sizes, int n_in,
                              void* d_out, int out_size, void* d_ws, size_t ws_size,
                              hipStream_t stream)
{
    const int N = in_sizes[0] / 512;   // 10000
    const int E = in_sizes[3];         // 320000

    const float* feat[3] = { (const float*)d_in[0], (const float*)d_in[1], (const float*)d_in[2] };
    const int* gsrc[4] = { (const int*)d_in[3], (const int*)d_in[5], (const int*)d_in[7], (const int*)d_in[9] };
    const int* gdst[4] = { (const int*)d_in[4], (const int*)d_in[6], (const int*)d_in[8], (const int*)d_in[10] };
    const float* W0[3] = { (const float*)d_in[11], (const float*)d_in[15], (const float*)d_in[19] };
    const float* B0[3] = { (const float*)d_in[12], (const float*)d_in[16], (const float*)d_in[20] };
    const float* W1[3] = { (const float*)d_in[13], (const float*)d_in[17], (const float*)d_in[21] };
    const float* B1[3] = { (const float*)d_in[14], (const float*)d_in[18], (const float*)d_in[22] };
    const float* fw[3] = { (const float*)d_in[23], (const float*)d_in[24], (const float*)d_in[25] };
    const float* fcw = (const float*)d_in[26];
    const float* fcb = (const float*)d_in[27];
    const float* wm0 = (const float*)d_in[28];
    const float* bm0 = (const float*)d_in[29];
    const float* wm1 = (const float*)d_in[30];
    const float* bm1 = (const float*)d_in[31];
    const float* decw = (const float*)d_in[32];
    float* out = (float*)d_out;

    // ---- workspace layout (floats) ----
    float* ws = (float*)d_ws;
    float* norms = ws;                           // 8N: [g0_out, g0_in, g1_out, g1_in, g2_out, g2_in, g_out, g_in]
    float* h512a = ws + (size_t)8 * N;           // N*512
    float* h512b = h512a + (size_t)N * 512;      // N*512
    float* hv0   = h512b + (size_t)N * 512;      // N*256
    float* hv1   = hv0 + (size_t)N * 256;        // N*256
    float* hv2   = hv1 + (size_t)N * 256;        // N*256
    float* ybuf  = hv2 + (size_t)N * 256;        // N*256
    float* xh256 = ybuf + (size_t)N * 256;       // N*256
    float* zbuf  = xh256 + (size_t)N * 256;      // N*128
    int* ip      = (int*)(zbuf + (size_t)N * 128);
    int* rowptr  = ip;                           // N+1
    int* cursor  = ip + (N + 1);                 // N
    int* colarr  = ip + (2 * N + 1);             // E

    const float* hv[3] = { hv0, hv1, hv2 };
    float* nout[4], *nin[4];
    for (int g = 0; g < 4; ++g) {
        nout[g] = norms + (size_t)g * 2 * N;
        nin[g]  = norms + (size_t)g * 2 * N + N;
    }

    // ---- norms for all 4 graphs ----
    hipMemsetAsync(norms, 0, (size_t)8 * N * sizeof(float), stream);
    for (int g = 0; g < 4; ++g)
        count_deg_f<<<(E + 255) / 256, 256, 0, stream>>>(gsrc[g], gdst[g], nout[g], nin[g], E);
    finalize_norm<<<(6 * N + 255) / 256, 256, 0, stream>>>(norms, 0.0f, 6 * N);
    finalize_norm<<<(2 * N + 255) / 256, 256, 0, stream>>>(norms + (size_t)6 * N, 1.0f, 2 * N); // fusion graph: +1 self loop

    auto buildCSR = [&](const int* s, const int* d) {
        hipMemsetAsync(cursor, 0, (size_t)N * sizeof(int), stream);
        count_int<<<(E + 255) / 256, 256, 0, stream>>>(d, cursor, E);
        scan_kernel<<<1, 1024, 0, stream>>>(cursor, rowptr, N);
        hipMemsetAsync(cursor, 0, (size_t)N * sizeof(int), stream);
        scatter_csr<<<(E + 255) / 256, 256, 0, stream>>>(s, d, rowptr, cursor, colarr, E);
    };

    auto gemm = [&](const float* A, const float* B, const float* scale, const float* bias,
                    float* C, int M_, int K_, int NC_, int acc_) {
        dim3 grid(NC_ / 64, (M_ + 63) / 64);
        gemm_kernel<<<grid, 256, 0, stream>>>(A, B, scale, bias, C, M_, K_, NC_, acc_);
    };

    // ---- per-view GCN stacks ----
    for (int v = 0; v < 3; ++v) {
        buildCSR(gsrc[v], gdst[v]);
        // layer 0: h = (x@W0)*n_out ; out = relu(agg*n_in + b0)
        gemm(feat[v], W0[v], nout[v], nullptr, h512a, N, 512, 512, 0);
        spmm_fused<512, 1, 0><<<N / 2, 256, 0, stream>>>(rowptr, colarr, h512a, nullptr, nin[v], B0[v], h512b, N);
        // layer 1: h = (h@W1)*n_out ; out = agg*n_in + b1
        gemm(h512b, W1[v], nout[v], nullptr, h512a /*tmp256*/, N, 512, 256, 0);
        spmm_fused<256, 0, 0><<<N / 4, 256, 0, stream>>>(rowptr, colarr, h512a, nullptr, nin[v], B1[v], (float*)hv[v], N);
    }

    // ---- FeatureFusion ----
    gemm(hv[0], fw[0], nullptr, nullptr, ybuf, N, 256, 256, 0);
    gemm(hv[1], fw[1], nullptr, nullptr, ybuf, N, 256, 256, 1);
    gemm(hv[2], fw[2], nullptr, nullptr, ybuf, N, 256, 256, 1);
    gemm(ybuf, fcw, nullptr, fcb, xh256, N, 256, 256, 0);

    // ---- fusion-graph GCN (self loops folded into epilogue) ----
    buildCSR(gsrc[3], gdst[3]);
    gemm(xh256, wm0, nout[3], nullptr, h512a /*tmp256*/, N, 256, 256, 0);
    spmm_fused<256, 1, 1><<<N / 4, 256, 0, stream>>>(rowptr, colarr, h512a, h512a, nin[3], bm0, h512b /*xh1*/, N);
    gemm(h512b, wm1, nout[3], nullptr, h512a /*tmp128*/, N, 256, 128, 0);
    float* xhf = out + (size_t)3 * N * N;
    spmm_fused<128, 0, 1><<<N / 8, 256, 0, stream>>>(rowptr, colarr, h512a, h512a, nin[3], bm1, xhf, N);

    // ---- decoder ----
    gemm(xhf, decw, nullptr, nullptr, zbuf, N, 128, 128, 0);
    dim3 agrid((N + 63) / 64, (N + 63) / 64);
    adj_kernel<<<agrid, 256, 0, stream>>>(zbuf, xhf, out, N);
}

// Round 2
// 2039.376 us; speedup vs baseline: 1.2740x; 1.2740x over previous
//
#include <hip/hip_runtime.h>
#include <hip/hip_bf16.h>
#include <cstdint>
#include <cstddef>

typedef __attribute__((ext_vector_type(8))) short s16x8;   // 8 bf16 in 4 VGPRs
typedef __attribute__((ext_vector_type(4))) float f32x4;

// ---------------- helpers ----------------

__device__ inline float sigmoidf_fast(float x) {
    return 1.0f / (1.0f + __expf(-x));
}

__device__ inline ushort f2bf_bits(float x) {
    __hip_bfloat16 h = __float2bfloat16(x);
    return *reinterpret_cast<ushort*>(&h);
}

// ---------------- degree / norm ----------------

__global__ void count_deg_f(const int* __restrict__ src, const int* __restrict__ dst,
                            float* __restrict__ dout, float* __restrict__ din, int E) {
    int i = blockIdx.x * 256 + threadIdx.x;
    if (i < E) {
        atomicAdd(&dout[src[i]], 1.0f);
        atomicAdd(&din[dst[i]], 1.0f);
    }
}

__global__ void finalize_norm(float* __restrict__ x, float add, int n) {
    int i = blockIdx.x * 256 + threadIdx.x;
    if (i < n) {
        float d = x[i] + add;
        x[i] = d > 0.0f ? rsqrtf(d) : 0.0f;
    }
}

// ---------------- CSR build ----------------

__global__ void count_int(const int* __restrict__ dst, int* __restrict__ cnt, int E) {
    int i = blockIdx.x * 256 + threadIdx.x;
    if (i < E) atomicAdd(&cnt[dst[i]], 1);
}

__global__ void scan_kernel(const int* __restrict__ counts, int* __restrict__ rowptr, int n) {
    __shared__ int partial[1024];
    int tid = threadIdx.x;
    int per = (n + 1023) >> 10;
    int start = tid * per;
    int s = 0;
    for (int i = 0; i < per; ++i) {
        int idx = start + i;
        if (idx < n) s += counts[idx];
    }
    partial[tid] = s;
    __syncthreads();
    for (int off = 1; off < 1024; off <<= 1) {
        int v = (tid >= off) ? partial[tid - off] : 0;
        __syncthreads();
        partial[tid] += v;
        __syncthreads();
    }
    int run = (tid > 0) ? partial[tid - 1] : 0;
    for (int i = 0; i < per; ++i) {
        int idx = start + i;
        if (idx < n) { rowptr[idx] = run; run += counts[idx]; }
    }
    if (tid == 1023) rowptr[n] = partial[1023];
}

__global__ void scatter_csr(const int* __restrict__ src, const int* __restrict__ dst,
                            const int* __restrict__ rowptr, int* __restrict__ cursor,
                            int* __restrict__ colout, int E) {
    int i = blockIdx.x * 256 + threadIdx.x;
    if (i < E) {
        int d = dst[i];
        int pos = atomicAdd(&cursor[d], 1);
        colout[rowptr[d] + pos] = src[i];
    }
}

// ---------------- generic fp32 GEMM: C = (A@B)*scale + bias [+C] ----------------

__global__ __launch_bounds__(256) void gemm_kernel(
    const float* __restrict__ A, const float* __restrict__ B,
    const float* __restrict__ scale, const float* __restrict__ bias,
    float* __restrict__ C, int M, int K, int NC, int accumulate)
{
    __shared__ float As[16][64];
    __shared__ float Bs[16][64];
    int tid = threadIdx.x;
    int tx = tid & 15, ty = tid >> 4;
    int rowBase = blockIdx.y * 64;
    int colBase = blockIdx.x * 64;

    int lm  = tid >> 2;          // A-tile row 0..63
    int lkq = (tid & 3) << 2;    // A-tile k quad 0,4,8,12
    int lk  = tid >> 4;          // B-tile k 0..15
    int lnq = (tid & 15) << 2;   // B-tile col quad

    int arow = rowBase + lm;
    if (arow >= M) arow = M - 1;

    float acc[4][4] = {};

    for (int k0 = 0; k0 < K; k0 += 16) {
        float4 av = *(const float4*)(A + (size_t)arow * K + (k0 + lkq));
        float4 bv = *(const float4*)(B + (size_t)(k0 + lk) * NC + colBase + lnq);
        As[lkq + 0][lm] = av.x;
        As[lkq + 1][lm] = av.y;
        As[lkq + 2][lm] = av.z;
        As[lkq + 3][lm] = av.w;
        *(float4*)&Bs[lk][lnq] = bv;
        __syncthreads();
#pragma unroll
        for (int k = 0; k < 16; ++k) {
            float4 a = *(const float4*)&As[k][ty << 2];
            float4 b = *(const float4*)&Bs[k][tx << 2];
            acc[0][0] += a.x * b.x; acc[0][1] += a.x * b.y; acc[0][2] += a.x * b.z; acc[0][3] += a.x * b.w;
            acc[1][0] += a.y * b.x; acc[1][1] += a.y * b.y; acc[1][2] += a.y * b.z; acc[1][3] += a.y * b.w;
            acc[2][0] += a.z * b.x; acc[2][1] += a.z * b.y; acc[2][2] += a.z * b.z; acc[2][3] += a.z * b.w;
            acc[3][0] += a.w * b.x; acc[3][1] += a.w * b.y; acc[3][2] += a.w * b.z; acc[3][3] += a.w * b.w;
        }
        __syncthreads();
    }

    int c = colBase + (tx << 2);
#pragma unroll
    for (int i = 0; i < 4; ++i) {
        int r = rowBase + (ty << 2) + i;
        if (r >= M) continue;
        float s = scale ? scale[r] : 1.0f;
        float4 o;
        o.x = acc[i][0] * s; o.y = acc[i][1] * s; o.z = acc[i][2] * s; o.w = acc[i][3] * s;
        if (bias) { o.x += bias[c]; o.y += bias[c + 1]; o.z += bias[c + 2]; o.w += bias[c + 3]; }
        float* cp = C + (size_t)r * NC + c;
        if (accumulate) {
            float4 old = *(const float4*)cp;
            o.x += old.x; o.y += old.y; o.z += old.z; o.w += old.w;
        }
        *(float4*)cp = o;
    }
}

// ---------------- fused gather SpMM + epilogue ----------------

template<int W, int RELU, int SELF>
__global__ __launch_bounds__(256) void spmm_fused(
    const int* __restrict__ rowptr, const int* __restrict__ col,
    const float* __restrict__ h, const float* __restrict__ selfh,
    const float* __restrict__ n_in, const float* __restrict__ bias,
    float* __restrict__ out, int M)
{
    constexpr int TPR = W / 4;       // threads per row (float4 lanes)
    constexpr int RPB = 256 / TPR;   // rows per block
    int lane = threadIdx.x & (TPR - 1);
    int r = blockIdx.x * RPB + (threadIdx.x / TPR);
    if (r >= M) return;
    int c = lane << 2;

    float4 acc = make_float4(0.f, 0.f, 0.f, 0.f);
    int beg = rowptr[r], end = rowptr[r + 1];
    for (int j = beg; j < end; ++j) {
        int s = col[j];
        float4 v = *(const float4*)(h + (size_t)s * W + c);
        acc.x += v.x; acc.y += v.y; acc.z += v.z; acc.w += v.w;
    }
    if (SELF) {
        float4 v = *(const float4*)(selfh + (size_t)r * W + c);
        acc.x += v.x; acc.y += v.y; acc.z += v.z; acc.w += v.w;
    }
    float ni = n_in[r];
    float4 b = *(const float4*)(bias + c);
    float4 o;
    o.x = acc.x * ni + b.x;
    o.y = acc.y * ni + b.y;
    o.z = acc.z * ni + b.z;
    o.w = acc.w * ni + b.w;
    if (RELU) {
        o.x = fmaxf(o.x, 0.f); o.y = fmaxf(o.y, 0.f);
        o.z = fmaxf(o.z, 0.f); o.w = fmaxf(o.w, 0.f);
    }
    *(float4*)(out + (size_t)r * W + c) = o;
}

// ---------------- fp32 -> bf16 convert (vectorized) ----------------

__global__ void f2bf_kernel(const float* __restrict__ in, ushort* __restrict__ out, int n4) {
    int i = blockIdx.x * 256 + threadIdx.x;
    if (i < n4) {
        float4 v = ((const float4*)in)[i];
        ushort4 o;
        o.x = f2bf_bits(v.x); o.y = f2bf_bits(v.y);
        o.z = f2bf_bits(v.z); o.w = f2bf_bits(v.w);
        ((ushort4*)out)[i] = o;
    }
}

// ---------------- decoder: bf16 MFMA, out[r,c] = sigmoid(dot(Z[r],X[c])), K=128 ----------------
// 128x128 tile/block, 4 waves (2x2), each wave 64x64 via 16x16x32 MFMA (4x4 frags).
// Fragments loaded directly from global (L2-resident), no LDS, no barriers.

__global__ __launch_bounds__(256) void adj_mfma(
    const ushort* __restrict__ Zb, const ushort* __restrict__ Xb,
    float* __restrict__ out, int M)
{
    int wave = threadIdx.x >> 6;       // 0..3
    int lane = threadIdx.x & 63;
    int wr = wave >> 1, wc = wave & 1;
    int rowBase = blockIdx.y * 128 + wr * 64;
    int colBase = blockIdx.x * 128 + wc * 64;
    int lr = lane & 15;                // fragment row/col within 16
    int kg = lane >> 4;                // k-group 0..3 (8 elems each)

    f32x4 acc[4][4] = {};

    // precompute clamped row/col bases
    int ar[4], bc[4];
#pragma unroll
    for (int m = 0; m < 4; ++m) {
        int r = rowBase + m * 16 + lr; ar[m] = (r < M) ? r : (M - 1);
        int c = colBase + m * 16 + lr; bc[m] = (c < M) ? c : (M - 1);
    }

#pragma unroll
    for (int ks = 0; ks < 4; ++ks) {
        s16x8 afr[4], bfr[4];
#pragma unroll
        for (int m = 0; m < 4; ++m)
            afr[m] = *(const s16x8*)(Zb + (size_t)ar[m] * 128 + ks * 32 + kg * 8);
#pragma unroll
        for (int n = 0; n < 4; ++n)
            bfr[n] = *(const s16x8*)(Xb + (size_t)bc[n] * 128 + ks * 32 + kg * 8);
#pragma unroll
        for (int m = 0; m < 4; ++m)
#pragma unroll
            for (int n = 0; n < 4; ++n)
                acc[m][n] = __builtin_amdgcn_mfma_f32_16x16x32_bf16(afr[m], bfr[n], acc[m][n], 0, 0, 0);
    }

    // epilogue: C[row=(lane>>4)*4+i (+16m)][col=lane&15 (+16n)]
    size_t NN = (size_t)M * M;
#pragma unroll
    for (int m = 0; m < 4; ++m) {
#pragma unroll
        for (int i = 0; i < 4; ++i) {
            int r = rowBase + m * 16 + kg * 4 + i;
            if (r >= M) continue;
            float* rowp = out + (size_t)r * M;
#pragma unroll
            for (int n = 0; n < 4; ++n) {
                int c = colBase + n * 16 + lr;
                if (c >= M) continue;
                float v = sigmoidf_fast(acc[m][n][i]);
                __builtin_nontemporal_store(v, rowp + c);
                __builtin_nontemporal_store(v, rowp + c + NN);
                __builtin_nontemporal_store(v, rowp + c + 2 * NN);
            }
        }
    }
}

// ---------------- launcher ----------------

extern "C" void kernel_launch(void* const* d_in, const int* in_sizes, int n_in,
                              void* d_out, int out_size, void* d_ws, size_t ws_size,
                              hipStream_t stream)
{
    const int N = in_sizes[0] / 512;   // 10000
    const int E = in_sizes[3];         // 320000

    const float* feat[3] = { (const float*)d_in[0], (const float*)d_in[1], (const float*)d_in[2] };
    const int* gsrc[4] = { (const int*)d_in[3], (const int*)d_in[5], (const int*)d_in[7], (const int*)d_in[9] };
    const int* gdst[4] = { (const int*)d_in[4], (const int*)d_in[6], (const int*)d_in[8], (const int*)d_in[10] };
    const float* W0[3] = { (const float*)d_in[11], (const float*)d_in[15], (const float*)d_in[19] };
    const float* B0[3] = { (const float*)d_in[12], (const float*)d_in[16], (const float*)d_in[20] };
    const float* W1[3] = { (const float*)d_in[13], (const float*)d_in[17], (const float*)d_in[21] };
    const float* B1[3] = { (const float*)d_in[14], (const float*)d_in[18], (const float*)d_in[22] };
    const float* fw[3] = { (const float*)d_in[23], (const float*)d_in[24], (const float*)d_in[25] };
    const float* fcw = (const float*)d_in[26];
    const float* fcb = (const float*)d_in[27];
    const float* wm0 = (const float*)d_in[28];
    const float* bm0 = (const float*)d_in[29];
    const float* wm1 = (const float*)d_in[30];
    const float* bm1 = (const float*)d_in[31];
    const float* decw = (const float*)d_in[32];
    float* out = (float*)d_out;

    // ---- workspace layout (floats) ----
    float* ws = (float*)d_ws;
    float* norms = ws;                           // 8N
    float* h512a = ws + (size_t)8 * N;           // N*512
    float* h512b = h512a + (size_t)N * 512;      // N*512
    float* hv0   = h512b + (size_t)N * 512;      // N*256
    float* hv1   = hv0 + (size_t)N * 256;        // N*256
    float* hv2   = hv1 + (size_t)N * 256;        // N*256
    float* ybuf  = hv2 + (size_t)N * 256;        // N*256
    float* xh256 = ybuf + (size_t)N * 256;       // N*256
    float* zbuf  = xh256 + (size_t)N * 256;      // N*128
    ushort* zb   = (ushort*)(zbuf + (size_t)N * 128); // N*128 bf16
    ushort* xb   = zb + (size_t)N * 128;              // N*128 bf16
    int* ip      = (int*)(xb + (size_t)N * 128);
    int* rowptr  = ip;                           // N+1
    int* cursor  = ip + (N + 1);                 // N
    int* colarr  = ip + (2 * N + 1);             // E

    const float* hv[3] = { hv0, hv1, hv2 };
    float* nout[4], *nin[4];
    for (int g = 0; g < 4; ++g) {
        nout[g] = norms + (size_t)g * 2 * N;
        nin[g]  = norms + (size_t)g * 2 * N + N;
    }

    // ---- norms for all 4 graphs ----
    hipMemsetAsync(norms, 0, (size_t)8 * N * sizeof(float), stream);
    for (int g = 0; g < 4; ++g)
        count_deg_f<<<(E + 255) / 256, 256, 0, stream>>>(gsrc[g], gdst[g], nout[g], nin[g], E);
    finalize_norm<<<(6 * N + 255) / 256, 256, 0, stream>>>(norms, 0.0f, 6 * N);
    finalize_norm<<<(2 * N + 255) / 256, 256, 0, stream>>>(norms + (size_t)6 * N, 1.0f, 2 * N);

    auto buildCSR = [&](const int* s, const int* d) {
        hipMemsetAsync(cursor, 0, (size_t)N * sizeof(int), stream);
        count_int<<<(E + 255) / 256, 256, 0, stream>>>(d, cursor, E);
        scan_kernel<<<1, 1024, 0, stream>>>(cursor, rowptr, N);
        hipMemsetAsync(cursor, 0, (size_t)N * sizeof(int), stream);
        scatter_csr<<<(E + 255) / 256, 256, 0, stream>>>(s, d, rowptr, cursor, colarr, E);
    };

    auto gemm = [&](const float* A, const float* B, const float* scale, const float* bias,
                    float* C, int M_, int K_, int NC_, int acc_) {
        dim3 grid(NC_ / 64, (M_ + 63) / 64);
        gemm_kernel<<<grid, 256, 0, stream>>>(A, B, scale, bias, C, M_, K_, NC_, acc_);
    };

    // ---- per-view GCN stacks ----
    for (int v = 0; v < 3; ++v) {
        buildCSR(gsrc[v], gdst[v]);
        gemm(feat[v], W0[v], nout[v], nullptr, h512a, N, 512, 512, 0);
        spmm_fused<512, 1, 0><<<N / 2, 256, 0, stream>>>(rowptr, colarr, h512a, nullptr, nin[v], B0[v], h512b, N);
        gemm(h512b, W1[v], nout[v], nullptr, h512a, N, 512, 256, 0);
        spmm_fused<256, 0, 0><<<N / 4, 256, 0, stream>>>(rowptr, colarr, h512a, nullptr, nin[v], B1[v], (float*)hv[v], N);
    }

    // ---- FeatureFusion ----
    gemm(hv[0], fw[0], nullptr, nullptr, ybuf, N, 256, 256, 0);
    gemm(hv[1], fw[1], nullptr, nullptr, ybuf, N, 256, 256, 1);
    gemm(hv[2], fw[2], nullptr, nullptr, ybuf, N, 256, 256, 1);
    gemm(ybuf, fcw, nullptr, fcb, xh256, N, 256, 256, 0);

    // ---- fusion-graph GCN (self loops folded into epilogue) ----
    buildCSR(gsrc[3], gdst[3]);
    gemm(xh256, wm0, nout[3], nullptr, h512a, N, 256, 256, 0);
    spmm_fused<256, 1, 1><<<N / 4, 256, 0, stream>>>(rowptr, colarr, h512a, h512a, nin[3], bm0, h512b, N);
    gemm(h512b, wm1, nout[3], nullptr, h512a, N, 256, 128, 0);
    float* xhf = out + (size_t)3 * N * N;
    spmm_fused<128, 0, 1><<<N / 8, 256, 0, stream>>>(rowptr, colarr, h512a, h512a, nin[3], bm1, xhf, N);

    // ---- decoder: Z = xhf @ decw; bf16 convert; MFMA adj ----
    gemm(xhf, decw, nullptr, nullptr, zbuf, N, 128, 128, 0);
    f2bf_kernel<<<(N * 128 / 4 + 255) / 256, 256, 0, stream>>>(zbuf, zb, N * 128 / 4);
    f2bf_kernel<<<(N * 128 / 4 + 255) / 256, 256, 0, stream>>>(xhf, xb, N * 128 / 4);
    dim3 agrid((N + 127) / 128, (N + 127) / 128);
    adj_mfma<<<agrid, 256, 0, stream>>>(zb, xb, out, N);
}

// Round 3
// 1289.858 us; speedup vs baseline: 2.0143x; 1.5811x over previous
//
#include <hip/hip_runtime.h>
#include <hip/hip_bf16.h>
#include <cstdint>
#include <cstddef>

typedef __attribute__((ext_vector_type(8))) short s16x8;   // 8 bf16 in 4 VGPRs
typedef __attribute__((ext_vector_type(4))) float f32x4;

// ---------------- helpers ----------------

__device__ inline float sigmoidf_fast(float x) {
    return 1.0f / (1.0f + __expf(-x));
}

__device__ inline ushort f2bf_bits(float x) {
    __hip_bfloat16 h = __float2bfloat16(x);
    return *reinterpret_cast<ushort*>(&h);
}

__device__ inline uint pk2bf(float a, float b) {
    return (uint)f2bf_bits(a) | ((uint)f2bf_bits(b) << 16);
}

// ---------------- degree / norm ----------------

__global__ void count_deg_f(const int* __restrict__ src, const int* __restrict__ dst,
                            float* __restrict__ dout, float* __restrict__ din, int E) {
    int i = blockIdx.x * 256 + threadIdx.x;
    if (i < E) {
        atomicAdd(&dout[src[i]], 1.0f);
        atomicAdd(&din[dst[i]], 1.0f);
    }
}

__global__ void finalize_norm(float* __restrict__ x, float add, int n) {
    int i = blockIdx.x * 256 + threadIdx.x;
    if (i < n) {
        float d = x[i] + add;
        x[i] = d > 0.0f ? rsqrtf(d) : 0.0f;
    }
}

// ---------------- CSR build ----------------

__global__ void count_int(const int* __restrict__ dst, int* __restrict__ cnt, int E) {
    int i = blockIdx.x * 256 + threadIdx.x;
    if (i < E) atomicAdd(&cnt[dst[i]], 1);
}

__global__ void scan_kernel(const int* __restrict__ counts, int* __restrict__ rowptr, int n) {
    __shared__ int partial[1024];
    int tid = threadIdx.x;
    int per = (n + 1023) >> 10;
    int start = tid * per;
    int s = 0;
    for (int i = 0; i < per; ++i) {
        int idx = start + i;
        if (idx < n) s += counts[idx];
    }
    partial[tid] = s;
    __syncthreads();
    for (int off = 1; off < 1024; off <<= 1) {
        int v = (tid >= off) ? partial[tid - off] : 0;
        __syncthreads();
        partial[tid] += v;
        __syncthreads();
    }
    int run = (tid > 0) ? partial[tid - 1] : 0;
    for (int i = 0; i < per; ++i) {
        int idx = start + i;
        if (idx < n) { rowptr[idx] = run; run += counts[idx]; }
    }
    if (tid == 1023) rowptr[n] = partial[1023];
}

__global__ void scatter_csr(const int* __restrict__ src, const int* __restrict__ dst,
                            const int* __restrict__ rowptr, int* __restrict__ cursor,
                            int* __restrict__ colout, int E) {
    int i = blockIdx.x * 256 + threadIdx.x;
    if (i < E) {
        int d = dst[i];
        int pos = atomicAdd(&cursor[d], 1);
        colout[rowptr[d] + pos] = src[i];
    }
}

// ---------------- fp32 -> bf16 convert (vectorized) ----------------

__global__ void f2bf_kernel(const float* __restrict__ in, ushort* __restrict__ out, int n4) {
    int i = blockIdx.x * 256 + threadIdx.x;
    if (i < n4) {
        float4 v = ((const float4*)in)[i];
        uint2 o;
        o.x = pk2bf(v.x, v.y);
        o.y = pk2bf(v.z, v.w);
        ((uint2*)out)[i] = o;
    }
}

// ---------------- weight transpose + convert: dst[n][colOff+k] = src[k][n] ----------------

__global__ void wtrans_kernel(const float* __restrict__ src, ushort* __restrict__ dst,
                              int K, int NC, int ldDst, int colOff) {
    int i = blockIdx.x * 256 + threadIdx.x;
    if (i >= K * NC) return;
    int k = i / NC, n = i - k * NC;
    dst[(size_t)n * ldDst + colOff + k] = f2bf_bits(src[i]);
}

// ---------------- bf16 MFMA GEMM: C[M,NC](bf16) = (A@B)*rowscale + bias ----------------
// A [M,K] bf16 row-major; B passed TRANSPOSED: BT [NC,K] bf16 row-major.
// 128x128 tile, 4 waves (2x2), 16x16x32 MFMA, XOR-swizzled LDS (byte ^= (row&7)<<4).

template<int HAS_SCALE, int HAS_BIAS>
__global__ __launch_bounds__(256) void gemm_bf16(
    const ushort* __restrict__ A, const ushort* __restrict__ BT,
    const float* __restrict__ rowscale, const float* __restrict__ bias,
    ushort* __restrict__ C, int M, int K, int NC)
{
    __shared__ ushort As[128 * 64];   // [row][k] swizzled, 16 KB
    __shared__ ushort Bs[128 * 64];   // [col][k] swizzled, 16 KB
    int tid = threadIdx.x;
    int wave = tid >> 6, lane = tid & 63;
    int wr = wave >> 1, wc = wave & 1;
    int rowBase = blockIdx.y * 128, colBase = blockIdx.x * 128;
    int lr = lane & 15, kg = lane >> 4;

    f32x4 acc[4][4] = {};

    for (int k0 = 0; k0 < K; k0 += 64) {
#pragma unroll
        for (int i = 0; i < 4; ++i) {
            int id = i * 256 + tid;
            int row = id >> 3;            // 0..127
            int co  = (id & 7) << 3;      // bf16 col offset 0..56
            int boff = ((row * 64 + co) << 1) ^ ((row & 7) << 4);
            int ar = rowBase + row; if (ar >= M) ar = M - 1;
            uint4 av = *(const uint4*)(A + (size_t)ar * K + k0 + co);
            *(uint4*)((char*)As + boff) = av;
            int bc = colBase + row;       // NC % 128 == 0, no guard
            uint4 bv = *(const uint4*)(BT + (size_t)bc * K + k0 + co);
            *(uint4*)((char*)Bs + boff) = bv;
        }
        __syncthreads();
#pragma unroll
        for (int ks = 0; ks < 2; ++ks) {
            s16x8 afr[4], bfr[4];
#pragma unroll
            for (int m = 0; m < 4; ++m) {
                int fr = wr * 64 + m * 16 + lr;
                int boff = ((fr * 64 + ks * 32 + kg * 8) << 1) ^ ((fr & 7) << 4);
                afr[m] = *(const s16x8*)((char*)As + boff);
            }
#pragma unroll
            for (int n = 0; n < 4; ++n) {
                int fc = wc * 64 + n * 16 + lr;
                int boff = ((fc * 64 + ks * 32 + kg * 8) << 1) ^ ((fc & 7) << 4);
                bfr[n] = *(const s16x8*)((char*)Bs + boff);
            }
#pragma unroll
            for (int m = 0; m < 4; ++m)
#pragma unroll
                for (int n = 0; n < 4; ++n)
                    acc[m][n] = __builtin_amdgcn_mfma_f32_16x16x32_bf16(afr[m], bfr[n], acc[m][n], 0, 0, 0);
        }
        __syncthreads();
    }

    // epilogue: C row = base + m*16 + kg*4 + i, col = base + n*16 + lr
#pragma unroll
    for (int m = 0; m < 4; ++m) {
#pragma unroll
        for (int i = 0; i < 4; ++i) {
            int r = rowBase + wr * 64 + m * 16 + kg * 4 + i;
            if (r >= M) continue;
            float s = HAS_SCALE ? rowscale[r] : 1.0f;
#pragma unroll
            for (int n = 0; n < 4; ++n) {
                int c = colBase + wc * 64 + n * 16 + lr;
                float v = acc[m][n][i] * s;
                if (HAS_BIAS) v += bias[c];
                C[(size_t)r * NC + c] = f2bf_bits(v);
            }
        }
    }
}

// ---------------- fused gather SpMM (bf16 in, fp32 accum) + epilogue ----------------
// out[r,:] = act((sum_{e: dst->r} h[src_e,:] + (SELF? h[r,:]:0)) * n_in[r] + bias)
// Writes bf16 always (next-GEMM input); OUTF32 additionally writes fp32.

template<int W, int RELU, int SELF, int OUTF32>
__global__ __launch_bounds__(256) void spmm_bf16(
    const int* __restrict__ rowptr, const int* __restrict__ col,
    const ushort* __restrict__ h,
    const float* __restrict__ n_in, const float* __restrict__ bias,
    ushort* __restrict__ outb, int ldOut, float* __restrict__ outf, int M)
{
    constexpr int TPR = W / 8;        // threads per row (8 bf16 per lane)
    constexpr int RPB = 256 / TPR;
    int lpr = threadIdx.x & (TPR - 1);
    int r = blockIdx.x * RPB + (threadIdx.x / TPR);
    if (r >= M) return;
    int c = lpr * 8;

    float acc[8] = {};
    int beg = rowptr[r], end = rowptr[r + 1];
    for (int j = beg; j < end; ++j) {
        int s = col[j];
        uint4 u = *(const uint4*)(h + (size_t)s * W + c);
        acc[0] += __uint_as_float(u.x << 16);
        acc[1] += __uint_as_float(u.x & 0xffff0000u);
        acc[2] += __uint_as_float(u.y << 16);
        acc[3] += __uint_as_float(u.y & 0xffff0000u);
        acc[4] += __uint_as_float(u.z << 16);
        acc[5] += __uint_as_float(u.z & 0xffff0000u);
        acc[6] += __uint_as_float(u.w << 16);
        acc[7] += __uint_as_float(u.w & 0xffff0000u);
    }
    if (SELF) {
        uint4 u = *(const uint4*)(h + (size_t)r * W + c);
        acc[0] += __uint_as_float(u.x << 16);
        acc[1] += __uint_as_float(u.x & 0xffff0000u);
        acc[2] += __uint_as_float(u.y << 16);
        acc[3] += __uint_as_float(u.y & 0xffff0000u);
        acc[4] += __uint_as_float(u.z << 16);
        acc[5] += __uint_as_float(u.z & 0xffff0000u);
        acc[6] += __uint_as_float(u.w << 16);
        acc[7] += __uint_as_float(u.w & 0xffff0000u);
    }
    float ni = n_in[r];
    float o[8];
    float4 b0 = *(const float4*)(bias + c);
    float4 b1 = *(const float4*)(bias + c + 4);
    o[0] = acc[0] * ni + b0.x; o[1] = acc[1] * ni + b0.y;
    o[2] = acc[2] * ni + b0.z; o[3] = acc[3] * ni + b0.w;
    o[4] = acc[4] * ni + b1.x; o[5] = acc[5] * ni + b1.y;
    o[6] = acc[6] * ni + b1.z; o[7] = acc[7] * ni + b1.w;
    if (RELU) {
#pragma unroll
        for (int j = 0; j < 8; ++j) o[j] = fmaxf(o[j], 0.f);
    }
    uint4 ob;
    ob.x = pk2bf(o[0], o[1]); ob.y = pk2bf(o[2], o[3]);
    ob.z = pk2bf(o[4], o[5]); ob.w = pk2bf(o[6], o[7]);
    *(uint4*)(outb + (size_t)r * ldOut + c) = ob;
    if (OUTF32) {
        float4 f0 = make_float4(o[0], o[1], o[2], o[3]);
        float4 f1 = make_float4(o[4], o[5], o[6], o[7]);
        *(float4*)(outf + (size_t)r * W + c) = f0;
        *(float4*)(outf + (size_t)r * W + c + 4) = f1;
    }
}

// ---------------- decoder: bf16 MFMA, out[r,c] = sigmoid(dot(Z[r],X[c])), K=128 ----------------

__global__ __launch_bounds__(256) void adj_mfma(
    const ushort* __restrict__ Zb, const ushort* __restrict__ Xb,
    float* __restrict__ out, int M)
{
    int wave = threadIdx.x >> 6;
    int lane = threadIdx.x & 63;
    int wr = wave >> 1, wc = wave & 1;
    int rowBase = blockIdx.y * 128 + wr * 64;
    int colBase = blockIdx.x * 128 + wc * 64;
    int lr = lane & 15;
    int kg = lane >> 4;

    f32x4 acc[4][4] = {};

    int ar[4], bc[4];
#pragma unroll
    for (int m = 0; m < 4; ++m) {
        int r = rowBase + m * 16 + lr; ar[m] = (r < M) ? r : (M - 1);
        int c = colBase + m * 16 + lr; bc[m] = (c < M) ? c : (M - 1);
    }

#pragma unroll
    for (int ks = 0; ks < 4; ++ks) {
        s16x8 afr[4], bfr[4];
#pragma unroll
        for (int m = 0; m < 4; ++m)
            afr[m] = *(const s16x8*)(Zb + (size_t)ar[m] * 128 + ks * 32 + kg * 8);
#pragma unroll
        for (int n = 0; n < 4; ++n)
            bfr[n] = *(const s16x8*)(Xb + (size_t)bc[n] * 128 + ks * 32 + kg * 8);
#pragma unroll
        for (int m = 0; m < 4; ++m)
#pragma unroll
            for (int n = 0; n < 4; ++n)
                acc[m][n] = __builtin_amdgcn_mfma_f32_16x16x32_bf16(afr[m], bfr[n], acc[m][n], 0, 0, 0);
    }

    size_t NN = (size_t)M * M;
#pragma unroll
    for (int m = 0; m < 4; ++m) {
#pragma unroll
        for (int i = 0; i < 4; ++i) {
            int r = rowBase + m * 16 + kg * 4 + i;
            if (r >= M) continue;
            float* rowp = out + (size_t)r * M;
#pragma unroll
            for (int n = 0; n < 4; ++n) {
                int c = colBase + n * 16 + lr;
                if (c >= M) continue;
                float v = sigmoidf_fast(acc[m][n][i]);
                __builtin_nontemporal_store(v, rowp + c);
                __builtin_nontemporal_store(v, rowp + c + NN);
                __builtin_nontemporal_store(v, rowp + c + 2 * NN);
            }
        }
    }
}

// ---------------- launcher ----------------

extern "C" void kernel_launch(void* const* d_in, const int* in_sizes, int n_in,
                              void* d_out, int out_size, void* d_ws, size_t ws_size,
                              hipStream_t stream)
{
    const int N = in_sizes[0] / 512;   // 10000
    const int E = in_sizes[3];         // 320000

    const float* feat[3] = { (const float*)d_in[0], (const float*)d_in[1], (const float*)d_in[2] };
    const int* gsrc[4] = { (const int*)d_in[3], (const int*)d_in[5], (const int*)d_in[7], (const int*)d_in[9] };
    const int* gdst[4] = { (const int*)d_in[4], (const int*)d_in[6], (const int*)d_in[8], (const int*)d_in[10] };
    const float* W0[3] = { (const float*)d_in[11], (const float*)d_in[15], (const float*)d_in[19] };
    const float* B0[3] = { (const float*)d_in[12], (const float*)d_in[16], (const float*)d_in[20] };
    const float* W1[3] = { (const float*)d_in[13], (const float*)d_in[17], (const float*)d_in[21] };
    const float* B1[3] = { (const float*)d_in[14], (const float*)d_in[18], (const float*)d_in[22] };
    const float* fw[3] = { (const float*)d_in[23], (const float*)d_in[24], (const float*)d_in[25] };
    const float* fcw = (const float*)d_in[26];
    const float* fcb = (const float*)d_in[27];
    const float* wm0 = (const float*)d_in[28];
    const float* bm0 = (const float*)d_in[29];
    const float* wm1 = (const float*)d_in[30];
    const float* bm1 = (const float*)d_in[31];
    const float* decw = (const float*)d_in[32];
    float* out = (float*)d_out;

    // ---- workspace layout (bytes, 256-aligned blocks) ----
    uint8_t* p = (uint8_t*)d_ws;
    auto alloc = [&](size_t bytes) { void* r = p; p += (bytes + 255) & ~(size_t)255; return r; };

    float*  norms  = (float*)alloc((size_t)8 * N * 4);
    ushort* featb0 = (ushort*)alloc((size_t)N * 512 * 2);
    ushort* featb1 = (ushort*)alloc((size_t)N * 512 * 2);
    ushort* featb2 = (ushort*)alloc((size_t)N * 512 * 2);
    ushort* featb[3] = { featb0, featb1, featb2 };
    ushort* w0T    = (ushort*)alloc((size_t)3 * 512 * 512 * 2);
    ushort* w1T    = (ushort*)alloc((size_t)3 * 256 * 512 * 2);
    ushort* fwT    = (ushort*)alloc((size_t)256 * 768 * 2);
    ushort* fcT    = (ushort*)alloc((size_t)256 * 256 * 2);
    ushort* wm0T   = (ushort*)alloc((size_t)256 * 256 * 2);
    ushort* wm1T   = (ushort*)alloc((size_t)128 * 256 * 2);
    ushort* decT   = (ushort*)alloc((size_t)128 * 128 * 2);
    ushort* h512   = (ushort*)alloc((size_t)N * 512 * 2);
    ushort* hb512  = (ushort*)alloc((size_t)N * 512 * 2);
    ushort* h256   = (ushort*)alloc((size_t)N * 256 * 2);
    ushort* hvcat  = (ushort*)alloc((size_t)N * 768 * 2);
    ushort* ybuf   = (ushort*)alloc((size_t)N * 256 * 2);
    ushort* xh256  = (ushort*)alloc((size_t)N * 256 * 2);
    ushort* m256   = (ushort*)alloc((size_t)N * 256 * 2);
    ushort* xh1    = (ushort*)alloc((size_t)N * 256 * 2);
    ushort* h128   = (ushort*)alloc((size_t)N * 128 * 2);
    ushort* xb     = (ushort*)alloc((size_t)N * 128 * 2);
    ushort* zb     = (ushort*)alloc((size_t)N * 128 * 2);
    int* rowptr    = (int*)alloc((size_t)(N + 1) * 4);
    int* cursor    = (int*)alloc((size_t)N * 4);
    int* colarr    = (int*)alloc((size_t)E * 4);

    float* nout[4], *nin[4];
    for (int g = 0; g < 4; ++g) {
        nout[g] = norms + (size_t)g * 2 * N;
        nin[g]  = norms + (size_t)g * 2 * N + N;
    }

    // ---- norms for all 4 graphs ----
    hipMemsetAsync(norms, 0, (size_t)8 * N * sizeof(float), stream);
    for (int g = 0; g < 4; ++g)
        count_deg_f<<<(E + 255) / 256, 256, 0, stream>>>(gsrc[g], gdst[g], nout[g], nin[g], E);
    finalize_norm<<<(6 * N + 255) / 256, 256, 0, stream>>>(norms, 0.0f, 6 * N);
    finalize_norm<<<(2 * N + 255) / 256, 256, 0, stream>>>(norms + (size_t)6 * N, 1.0f, 2 * N);

    // ---- convert features + weights ----
    for (int v = 0; v < 3; ++v)
        f2bf_kernel<<<(N * 512 / 4 + 255) / 256, 256, 0, stream>>>(feat[v], featb[v], N * 512 / 4);
    auto wtrans = [&](const float* src, ushort* dst, int K, int NC, int ld, int off) {
        wtrans_kernel<<<(K * NC + 255) / 256, 256, 0, stream>>>(src, dst, K, NC, ld, off);
    };
    for (int v = 0; v < 3; ++v) {
        wtrans(W0[v], w0T + (size_t)v * 512 * 512, 512, 512, 512, 0);
        wtrans(W1[v], w1T + (size_t)v * 256 * 512, 512, 256, 512, 0);
        wtrans(fw[v], fwT, 256, 256, 768, 256 * v);
    }
    wtrans(fcw, fcT, 256, 256, 256, 0);
    wtrans(wm0, wm0T, 256, 256, 256, 0);
    wtrans(wm1, wm1T, 256, 128, 256, 0);
    wtrans(decw, decT, 128, 128, 128, 0);

    auto buildCSR = [&](const int* s, const int* d) {
        hipMemsetAsync(cursor, 0, (size_t)N * sizeof(int), stream);
        count_int<<<(E + 255) / 256, 256, 0, stream>>>(d, cursor, E);
        scan_kernel<<<1, 1024, 0, stream>>>(cursor, rowptr, N);
        hipMemsetAsync(cursor, 0, (size_t)N * sizeof(int), stream);
        scatter_csr<<<(E + 255) / 256, 256, 0, stream>>>(s, d, rowptr, cursor, colarr, E);
    };

    auto gemm = [&](const ushort* A, const ushort* BT, const float* scale, const float* bias,
                    ushort* C, int K, int NC) {
        dim3 grid(NC / 128, (N + 127) / 128);
        if (scale)
            gemm_bf16<1, 0><<<grid, 256, 0, stream>>>(A, BT, scale, nullptr, C, N, K, NC);
        else if (bias)
            gemm_bf16<0, 1><<<grid, 256, 0, stream>>>(A, BT, nullptr, bias, C, N, K, NC);
        else
            gemm_bf16<0, 0><<<grid, 256, 0, stream>>>(A, BT, nullptr, nullptr, C, N, K, NC);
    };

    // ---- per-view GCN stacks ----
    for (int v = 0; v < 3; ++v) {
        buildCSR(gsrc[v], gdst[v]);
        gemm(featb[v], w0T + (size_t)v * 512 * 512, nout[v], nullptr, h512, 512, 512);
        spmm_bf16<512, 1, 0, 0><<<(N + 3) / 4, 256, 0, stream>>>(
            rowptr, colarr, h512, nin[v], B0[v], hb512, 512, nullptr, N);
        gemm(hb512, w1T + (size_t)v * 256 * 512, nout[v], nullptr, h256, 512, 256);
        spmm_bf16<256, 0, 0, 0><<<(N + 7) / 8, 256, 0, stream>>>(
            rowptr, colarr, h256, nin[v], B1[v], hvcat + 256 * v, 768, nullptr, N);
    }

    // ---- FeatureFusion: y = [h0|h1|h2] @ [fw1;fw2;fw3]; xh = y@fcw + fcb ----
    gemm(hvcat, fwT, nullptr, nullptr, ybuf, 768, 256);
    gemm(ybuf, fcT, nullptr, fcb, xh256, 256, 256);

    // ---- fusion-graph GCN (self loops folded into epilogue) ----
    buildCSR(gsrc[3], gdst[3]);
    gemm(xh256, wm0T, nout[3], nullptr, m256, 256, 256);
    spmm_bf16<256, 1, 1, 0><<<(N + 7) / 8, 256, 0, stream>>>(
        rowptr, colarr, m256, nin[3], bm0, xh1, 256, nullptr, N);
    gemm(xh1, wm1T, nout[3], nullptr, h128, 256, 128);
    float* xhf = out + (size_t)3 * N * N;
    spmm_bf16<128, 0, 1, 1><<<(N + 15) / 16, 256, 0, stream>>>(
        rowptr, colarr, h128, nin[3], bm1, xb, 128, xhf, N);

    // ---- decoder ----
    gemm(xb, decT, nullptr, nullptr, zb, 128, 128);
    dim3 agrid((N + 127) / 128, (N + 127) / 128);
    adj_mfma<<<agrid, 256, 0, stream>>>(zb, xb, out, N);
}

// Round 4
// 904.197 us; speedup vs baseline: 2.8735x; 1.4265x over previous
//
#include <hip/hip_runtime.h>
#include <hip/hip_bf16.h>
#include <cstdint>
#include <cstddef>

typedef __attribute__((ext_vector_type(8))) short s16x8;   // 8 bf16 in 4 VGPRs
typedef __attribute__((ext_vector_type(4))) float f32x4;

// ---------------- helpers ----------------

__device__ inline float sigmoidf_fast(float x) {
    return 1.0f / (1.0f + __expf(-x));
}

__device__ inline ushort f2bf_bits(float x) {
    __hip_bfloat16 h = __float2bfloat16(x);
    return *reinterpret_cast<ushort*>(&h);
}

__device__ inline uint pk2bf(float a, float b) {
    return (uint)f2bf_bits(a) | ((uint)f2bf_bits(b) << 16);
}

// ---------------- batched convert / transpose ----------------

__global__ void f2bf3(const float* __restrict__ s0, const float* __restrict__ s1,
                      const float* __restrict__ s2, ushort* __restrict__ dst, int n4) {
    int z = blockIdx.y;
    const float* src = z == 0 ? s0 : (z == 1 ? s1 : s2);
    int i = blockIdx.x * 256 + threadIdx.x;
    if (i < n4) {
        float4 v = ((const float4*)src)[i];
        uint2 o;
        o.x = pk2bf(v.x, v.y);
        o.y = pk2bf(v.z, v.w);
        ((uint2*)(dst + (size_t)z * n4 * 4))[i] = o;
    }
}

// dst[z*dstStrideZ + n*ldDst + colOffPerZ*z + k] = src_z[k*NC + n]
__global__ void wtrans3(const float* __restrict__ s0, const float* __restrict__ s1,
                        const float* __restrict__ s2, ushort* __restrict__ dst,
                        int K, int NC, int ldDst, int colOffPerZ, size_t dstStrideZ) {
    int z = blockIdx.y;
    const float* src = z == 0 ? s0 : (z == 1 ? s1 : s2);
    int i = blockIdx.x * 256 + threadIdx.x;
    if (i >= K * NC) return;
    int k = i / NC, n = i - k * NC;
    dst[(size_t)z * dstStrideZ + (size_t)n * ldDst + colOffPerZ * z + k] = f2bf_bits(src[i]);
}

// ---------------- one-pass degree counts for all 4 graphs ----------------

__global__ void count_all(const int* __restrict__ s0, const int* __restrict__ d0,
                          const int* __restrict__ s1, const int* __restrict__ d1,
                          const int* __restrict__ s2, const int* __restrict__ d2,
                          const int* __restrict__ s3, const int* __restrict__ d3,
                          int* __restrict__ cntOut, int* __restrict__ cntIn, int E, int N) {
    int i = blockIdx.x * 256 + threadIdx.x;
    if (i >= E) return;
    atomicAdd(&cntOut[s0[i]], 1);          atomicAdd(&cntIn[d0[i]], 1);
    atomicAdd(&cntOut[N + s1[i]], 1);      atomicAdd(&cntIn[N + d1[i]], 1);
    atomicAdd(&cntOut[2 * N + s2[i]], 1);  atomicAdd(&cntIn[2 * N + d2[i]], 1);
    atomicAdd(&cntOut[3 * N + s3[i]], 1);  atomicAdd(&cntIn[3 * N + d3[i]], 1);
}

// norms[g][0][r] = rsqrt(deg_out), norms[g][1][r] = rsqrt(deg_in); fusion graph (g=3) +1 self loop
__global__ void norm_all(const int* __restrict__ cntOut, const int* __restrict__ cntIn,
                         float* __restrict__ norms, int N) {
    int i = blockIdx.x * 256 + threadIdx.x;
    if (i >= 8 * N) return;
    int g = i / (2 * N);
    int rem = i - g * 2 * N;
    int half = rem / N;
    int r = rem - half * N;
    int c = (half ? cntIn : cntOut)[g * N + r] + (g == 3 ? 1 : 0);
    norms[i] = c > 0 ? rsqrtf((float)c) : 0.0f;
}

// ---------------- CSR: scan (4 graphs, 1 block each) + batched scatter ----------------

__global__ void scan4(const int* __restrict__ cntIn, int* __restrict__ rp4, int N) {
    __shared__ int partial[1024];
    int g = blockIdx.x;
    const int* counts = cntIn + (size_t)g * N;
    int* rowptr = rp4 + (size_t)g * (N + 1);
    int tid = threadIdx.x;
    int per = (N + 1023) >> 10;
    int start = tid * per;
    int s = 0;
    for (int i = 0; i < per; ++i) {
        int idx = start + i;
        if (idx < N) s += counts[idx];
    }
    partial[tid] = s;
    __syncthreads();
    for (int off = 1; off < 1024; off <<= 1) {
        int v = (tid >= off) ? partial[tid - off] : 0;
        __syncthreads();
        partial[tid] += v;
        __syncthreads();
    }
    int run = (tid > 0) ? partial[tid - 1] : 0;
    for (int i = 0; i < per; ++i) {
        int idx = start + i;
        if (idx < N) { rowptr[idx] = run; run += counts[idx]; }
    }
    if (tid == 1023) rowptr[N] = partial[1023];
}

__global__ void scatter4(const int* __restrict__ s0, const int* __restrict__ d0,
                         const int* __restrict__ s1, const int* __restrict__ d1,
                         const int* __restrict__ s2, const int* __restrict__ d2,
                         const int* __restrict__ s3, const int* __restrict__ d3,
                         const int* __restrict__ rp4, int* __restrict__ cursor4,
                         int* __restrict__ col4, int E, int N) {
    int g = blockIdx.y;
    const int* ss[4] = { s0, s1, s2, s3 };
    const int* dd[4] = { d0, d1, d2, d3 };
    int i = blockIdx.x * 256 + threadIdx.x;
    if (i >= E) return;
    int d = dd[g][i];
    int pos = atomicAdd(&cursor4[g * N + d], 1);
    col4[(size_t)g * E + rp4[(size_t)g * (N + 1) + d] + pos] = ss[g][i];
}

// ---------------- bf16 MFMA GEMM (batched via grid.z) ----------------
// C[M,NC](bf16) = (A@B)*rowscale + bias ; BT is B transposed [NC,K] bf16.
// 128x128 tile, 4 waves (2x2), 16x16x32 MFMA, XOR-swizzled LDS (byte ^= (row&7)<<4).

template<int HAS_SCALE, int HAS_BIAS>
__global__ __launch_bounds__(256) void gemm_bf16(
    const ushort* __restrict__ A, const ushort* __restrict__ BT,
    const float* __restrict__ rowscale, const float* __restrict__ bias,
    ushort* __restrict__ C, int M, int K, int NC,
    size_t aStride, size_t btStride, size_t cStride, int sStride)
{
    int v = blockIdx.z;
    A += (size_t)v * aStride;
    BT += (size_t)v * btStride;
    C += (size_t)v * cStride;
    if (HAS_SCALE) rowscale += (size_t)v * sStride;

    __shared__ ushort As[128 * 64];
    __shared__ ushort Bs[128 * 64];
    int tid = threadIdx.x;
    int wave = tid >> 6, lane = tid & 63;
    int wr = wave >> 1, wc = wave & 1;
    int rowBase = blockIdx.y * 128, colBase = blockIdx.x * 128;
    int lr = lane & 15, kg = lane >> 4;

    f32x4 acc[4][4] = {};

    for (int k0 = 0; k0 < K; k0 += 64) {
#pragma unroll
        for (int i = 0; i < 4; ++i) {
            int id = i * 256 + tid;
            int row = id >> 3;
            int co  = (id & 7) << 3;
            int boff = ((row * 64 + co) << 1) ^ ((row & 7) << 4);
            int ar = rowBase + row; if (ar >= M) ar = M - 1;
            uint4 av = *(const uint4*)(A + (size_t)ar * K + k0 + co);
            *(uint4*)((char*)As + boff) = av;
            int bc = colBase + row;
            uint4 bv = *(const uint4*)(BT + (size_t)bc * K + k0 + co);
            *(uint4*)((char*)Bs + boff) = bv;
        }
        __syncthreads();
#pragma unroll
        for (int ks = 0; ks < 2; ++ks) {
            s16x8 afr[4], bfr[4];
#pragma unroll
            for (int m = 0; m < 4; ++m) {
                int fr = wr * 64 + m * 16 + lr;
                int boff = ((fr * 64 + ks * 32 + kg * 8) << 1) ^ ((fr & 7) << 4);
                afr[m] = *(const s16x8*)((char*)As + boff);
            }
#pragma unroll
            for (int n = 0; n < 4; ++n) {
                int fc = wc * 64 + n * 16 + lr;
                int boff = ((fc * 64 + ks * 32 + kg * 8) << 1) ^ ((fc & 7) << 4);
                bfr[n] = *(const s16x8*)((char*)Bs + boff);
            }
#pragma unroll
            for (int m = 0; m < 4; ++m)
#pragma unroll
                for (int n = 0; n < 4; ++n)
                    acc[m][n] = __builtin_amdgcn_mfma_f32_16x16x32_bf16(afr[m], bfr[n], acc[m][n], 0, 0, 0);
        }
        __syncthreads();
    }

#pragma unroll
    for (int m = 0; m < 4; ++m) {
#pragma unroll
        for (int i = 0; i < 4; ++i) {
            int r = rowBase + wr * 64 + m * 16 + kg * 4 + i;
            if (r >= M) continue;
            float s = HAS_SCALE ? rowscale[r] : 1.0f;
#pragma unroll
            for (int n = 0; n < 4; ++n) {
                int c = colBase + wc * 64 + n * 16 + lr;
                float vv = acc[m][n][i] * s;
                if (HAS_BIAS) vv += bias[c];
                C[(size_t)r * NC + c] = f2bf_bits(vv);
            }
        }
    }
}

// ---------------- fused gather SpMM (bf16 in, fp32 accum), batched via grid.y ----------------

#define ACC8(u) { acc[0]+=__uint_as_float(u.x<<16); acc[1]+=__uint_as_float(u.x&0xffff0000u); \
                  acc[2]+=__uint_as_float(u.y<<16); acc[3]+=__uint_as_float(u.y&0xffff0000u); \
                  acc[4]+=__uint_as_float(u.z<<16); acc[5]+=__uint_as_float(u.z&0xffff0000u); \
                  acc[6]+=__uint_as_float(u.w<<16); acc[7]+=__uint_as_float(u.w&0xffff0000u); }

template<int W, int RELU, int SELF, int OUTF32>
__global__ __launch_bounds__(256) void spmm_bf16(
    const int* __restrict__ rp4, const int* __restrict__ col4,
    const ushort* __restrict__ hB, const float* __restrict__ normB,
    const float* __restrict__ b0v, const float* __restrict__ b1v, const float* __restrict__ b2v,
    ushort* __restrict__ outB, float* __restrict__ outf,
    int M, int E, size_t hStride, int ninStride, size_t outStride, int ldOut, int colOffPerV)
{
    constexpr int TPR = W / 8;
    constexpr int RPB = 256 / TPR;
    int v = blockIdx.y;
    const int* rowptr = rp4 + (size_t)v * (M + 1);
    const int* col = col4 + (size_t)v * E;
    const ushort* h = hB + (size_t)v * hStride;
    const float* n_in = normB + (size_t)v * ninStride + M;
    const float* bias = (v == 0) ? b0v : (v == 1 ? b1v : b2v);
    ushort* outb = outB + (size_t)v * outStride;
    int cOff = colOffPerV * v;

    int lpr = threadIdx.x & (TPR - 1);
    int r = blockIdx.x * RPB + (threadIdx.x / TPR);
    if (r >= M) return;
    int c = lpr * 8;

    float acc[8] = {};
    int beg = rowptr[r], end = rowptr[r + 1];
    int j = beg;
    for (; j + 3 < end; j += 4) {
        int sA = col[j], sB = col[j + 1], sC = col[j + 2], sD = col[j + 3];
        uint4 uA = *(const uint4*)(h + (size_t)sA * W + c);
        uint4 uB = *(const uint4*)(h + (size_t)sB * W + c);
        uint4 uC = *(const uint4*)(h + (size_t)sC * W + c);
        uint4 uD = *(const uint4*)(h + (size_t)sD * W + c);
        ACC8(uA); ACC8(uB); ACC8(uC); ACC8(uD);
    }
    for (; j < end; ++j) {
        int s = col[j];
        uint4 u = *(const uint4*)(h + (size_t)s * W + c);
        ACC8(u);
    }
    if (SELF) {
        uint4 u = *(const uint4*)(h + (size_t)r * W + c);
        ACC8(u);
    }
    float ni = n_in[r];
    float o[8];
    float4 bb0 = *(const float4*)(bias + c);
    float4 bb1 = *(const float4*)(bias + c + 4);
    o[0] = acc[0] * ni + bb0.x; o[1] = acc[1] * ni + bb0.y;
    o[2] = acc[2] * ni + bb0.z; o[3] = acc[3] * ni + bb0.w;
    o[4] = acc[4] * ni + bb1.x; o[5] = acc[5] * ni + bb1.y;
    o[6] = acc[6] * ni + bb1.z; o[7] = acc[7] * ni + bb1.w;
    if (RELU) {
#pragma unroll
        for (int q = 0; q < 8; ++q) o[q] = fmaxf(o[q], 0.f);
    }
    uint4 ob;
    ob.x = pk2bf(o[0], o[1]); ob.y = pk2bf(o[2], o[3]);
    ob.z = pk2bf(o[4], o[5]); ob.w = pk2bf(o[6], o[7]);
    *(uint4*)(outb + (size_t)r * ldOut + cOff + c) = ob;
    if (OUTF32) {
        *(float4*)(outf + (size_t)r * W + c) = make_float4(o[0], o[1], o[2], o[3]);
        *(float4*)(outf + (size_t)r * W + c + 4) = make_float4(o[4], o[5], o[6], o[7]);
    }
}

// ---------------- decoder: bf16 MFMA, out[r,c] = sigmoid(dot(Z[r],X[c])), K=128 ----------------

__global__ __launch_bounds__(256) void adj_mfma(
    const ushort* __restrict__ Zb, const ushort* __restrict__ Xb,
    float* __restrict__ out, int M)
{
    int wave = threadIdx.x >> 6;
    int lane = threadIdx.x & 63;
    int wr = wave >> 1, wc = wave & 1;
    int rowBase = blockIdx.y * 128 + wr * 64;
    int colBase = blockIdx.x * 128 + wc * 64;
    int lr = lane & 15;
    int kg = lane >> 4;

    f32x4 acc[4][4] = {};

    int ar[4], bc[4];
#pragma unroll
    for (int m = 0; m < 4; ++m) {
        int r = rowBase + m * 16 + lr; ar[m] = (r < M) ? r : (M - 1);
        int c = colBase + m * 16 + lr; bc[m] = (c < M) ? c : (M - 1);
    }

#pragma unroll
    for (int ks = 0; ks < 4; ++ks) {
        s16x8 afr[4], bfr[4];
#pragma unroll
        for (int m = 0; m < 4; ++m)
            afr[m] = *(const s16x8*)(Zb + (size_t)ar[m] * 128 + ks * 32 + kg * 8);
#pragma unroll
        for (int n = 0; n < 4; ++n)
            bfr[n] = *(const s16x8*)(Xb + (size_t)bc[n] * 128 + ks * 32 + kg * 8);
#pragma unroll
        for (int m = 0; m < 4; ++m)
#pragma unroll
            for (int n = 0; n < 4; ++n)
                acc[m][n] = __builtin_amdgcn_mfma_f32_16x16x32_bf16(afr[m], bfr[n], acc[m][n], 0, 0, 0);
    }

    size_t NN = (size_t)M * M;
#pragma unroll
    for (int m = 0; m < 4; ++m) {
#pragma unroll
        for (int i = 0; i < 4; ++i) {
            int r = rowBase + m * 16 + kg * 4 + i;
            if (r >= M) continue;
            float* rowp = out + (size_t)r * M;
#pragma unroll
            for (int n = 0; n < 4; ++n) {
                int c = colBase + n * 16 + lr;
                if (c >= M) continue;
                float v = sigmoidf_fast(acc[m][n][i]);
                __builtin_nontemporal_store(v, rowp + c);
                __builtin_nontemporal_store(v, rowp + c + NN);
                __builtin_nontemporal_store(v, rowp + c + 2 * NN);
            }
        }
    }
}

// ---------------- launcher ----------------

extern "C" void kernel_launch(void* const* d_in, const int* in_sizes, int n_in,
                              void* d_out, int out_size, void* d_ws, size_t ws_size,
                              hipStream_t stream)
{
    const int N = in_sizes[0] / 512;   // 10000
    const int E = in_sizes[3];         // 320000

    const float* feat[3] = { (const float*)d_in[0], (const float*)d_in[1], (const float*)d_in[2] };
    const int* gsrc[4] = { (const int*)d_in[3], (const int*)d_in[5], (const int*)d_in[7], (const int*)d_in[9] };
    const int* gdst[4] = { (const int*)d_in[4], (const int*)d_in[6], (const int*)d_in[8], (const int*)d_in[10] };
    const float* W0[3] = { (const float*)d_in[11], (const float*)d_in[15], (const float*)d_in[19] };
    const float* B0[3] = { (const float*)d_in[12], (const float*)d_in[16], (const float*)d_in[20] };
    const float* W1[3] = { (const float*)d_in[13], (const float*)d_in[17], (const float*)d_in[21] };
    const float* B1[3] = { (const float*)d_in[14], (const float*)d_in[18], (const float*)d_in[22] };
    const float* fw[3] = { (const float*)d_in[23], (const float*)d_in[24], (const float*)d_in[25] };
    const float* fcw = (const float*)d_in[26];
    const float* fcb = (const float*)d_in[27];
    const float* wm0 = (const float*)d_in[28];
    const float* bm0 = (const float*)d_in[29];
    const float* wm1 = (const float*)d_in[30];
    const float* bm1 = (const float*)d_in[31];
    const float* decw = (const float*)d_in[32];
    float* out = (float*)d_out;

    // ---- workspace layout ----
    uint8_t* p = (uint8_t*)d_ws;
    auto alloc = [&](size_t bytes) { void* r = p; p += (bytes + 255) & ~(size_t)255; return r; };

    float*  norms   = (float*)alloc((size_t)8 * N * 4);
    ushort* featb   = (ushort*)alloc((size_t)3 * N * 512 * 2);
    ushort* w0T     = (ushort*)alloc((size_t)3 * 512 * 512 * 2);
    ushort* w1T     = (ushort*)alloc((size_t)3 * 256 * 512 * 2);
    ushort* fwT     = (ushort*)alloc((size_t)256 * 768 * 2);
    ushort* fcT     = (ushort*)alloc((size_t)256 * 256 * 2);
    ushort* wm0T    = (ushort*)alloc((size_t)256 * 256 * 2);
    ushort* wm1T    = (ushort*)alloc((size_t)128 * 256 * 2);
    ushort* decT    = (ushort*)alloc((size_t)128 * 128 * 2);
    ushort* h512_3  = (ushort*)alloc((size_t)3 * N * 512 * 2);
    ushort* hb512_3 = (ushort*)alloc((size_t)3 * N * 512 * 2);
    ushort* h256_3  = (ushort*)alloc((size_t)3 * N * 256 * 2);
    ushort* hvcat   = (ushort*)alloc((size_t)N * 768 * 2);
    ushort* ybuf    = (ushort*)alloc((size_t)N * 256 * 2);
    ushort* xh256   = (ushort*)alloc((size_t)N * 256 * 2);
    ushort* m256    = (ushort*)alloc((size_t)N * 256 * 2);
    ushort* xh1     = (ushort*)alloc((size_t)N * 256 * 2);
    ushort* h128    = (ushort*)alloc((size_t)N * 128 * 2);
    ushort* xb      = (ushort*)alloc((size_t)N * 128 * 2);
    ushort* zb      = (ushort*)alloc((size_t)N * 128 * 2);
    int* cntOut     = (int*)alloc((size_t)4 * N * 4);     // contiguous with cntIn+cursor
    int* cntIn      = (int*)alloc((size_t)4 * N * 4);
    int* cursor4    = (int*)alloc((size_t)4 * N * 4);
    int* rp4        = (int*)alloc((size_t)4 * (N + 1) * 4);
    int* col4       = (int*)alloc((size_t)4 * E * 4);

    // ---- converts ----
    {
        dim3 g((N * 512 / 4 + 255) / 256, 3);
        f2bf3<<<g, 256, 0, stream>>>(feat[0], feat[1], feat[2], featb, N * 512 / 4);
    }
    wtrans3<<<dim3((512 * 512 + 255) / 256, 3), 256, 0, stream>>>(W0[0], W0[1], W0[2], w0T, 512, 512, 512, 0, (size_t)512 * 512);
    wtrans3<<<dim3((512 * 256 + 255) / 256, 3), 256, 0, stream>>>(W1[0], W1[1], W1[2], w1T, 512, 256, 512, 0, (size_t)256 * 512);
    wtrans3<<<dim3((256 * 256 + 255) / 256, 3), 256, 0, stream>>>(fw[0], fw[1], fw[2], fwT, 256, 256, 768, 256, 0);
    wtrans3<<<dim3((256 * 256 + 255) / 256, 1), 256, 0, stream>>>(fcw, fcw, fcw, fcT, 256, 256, 256, 0, 0);
    wtrans3<<<dim3((256 * 256 + 255) / 256, 1), 256, 0, stream>>>(wm0, wm0, wm0, wm0T, 256, 256, 256, 0, 0);
    wtrans3<<<dim3((256 * 128 + 255) / 256, 1), 256, 0, stream>>>(wm1, wm1, wm1, wm1T, 256, 128, 256, 0, 0);
    wtrans3<<<dim3((128 * 128 + 255) / 256, 1), 256, 0, stream>>>(decw, decw, decw, decT, 128, 128, 128, 0, 0);

    // ---- graph prep: counts -> norms + CSR (all 4 graphs) ----
    hipMemsetAsync(cntOut, 0, (size_t)12 * N * 4, stream);   // cntOut+cntIn+cursor4
    count_all<<<(E + 255) / 256, 256, 0, stream>>>(
        gsrc[0], gdst[0], gsrc[1], gdst[1], gsrc[2], gdst[2], gsrc[3], gdst[3], cntOut, cntIn, E, N);
    norm_all<<<(8 * N + 255) / 256, 256, 0, stream>>>(cntOut, cntIn, norms, N);
    scan4<<<4, 1024, 0, stream>>>(cntIn, rp4, N);
    scatter4<<<dim3((E + 255) / 256, 4), 256, 0, stream>>>(
        gsrc[0], gdst[0], gsrc[1], gdst[1], gsrc[2], gdst[2], gsrc[3], gdst[3],
        rp4, cursor4, col4, E, N);

    // ---- per-view GCN stacks (batched over 3 views) ----
    // layer 0: h = (x@W0)*n_out ; relu(agg*n_in + b0)
    gemm_bf16<1, 0><<<dim3(4, (N + 127) / 128, 3), 256, 0, stream>>>(
        featb, w0T, norms, nullptr, h512_3, N, 512, 512,
        (size_t)N * 512, (size_t)512 * 512, (size_t)N * 512, 2 * N);
    spmm_bf16<512, 1, 0, 0><<<dim3((N + 3) / 4, 3), 256, 0, stream>>>(
        rp4, col4, h512_3, norms, B0[0], B0[1], B0[2], hb512_3, nullptr,
        N, E, (size_t)N * 512, 2 * N, (size_t)N * 512, 512, 0);
    // layer 1
    gemm_bf16<1, 0><<<dim3(2, (N + 127) / 128, 3), 256, 0, stream>>>(
        hb512_3, w1T, norms, nullptr, h256_3, N, 512, 256,
        (size_t)N * 512, (size_t)256 * 512, (size_t)N * 256, 2 * N);
    spmm_bf16<256, 0, 0, 0><<<dim3((N + 7) / 8, 3), 256, 0, stream>>>(
        rp4, col4, h256_3, norms, B1[0], B1[1], B1[2], hvcat, nullptr,
        N, E, (size_t)N * 256, 2 * N, 0, 768, 256);

    // ---- FeatureFusion: y = [h0|h1|h2] @ [fw1;fw2;fw3]; xh = y@fcw + fcb ----
    gemm_bf16<0, 0><<<dim3(2, (N + 127) / 128, 1), 256, 0, stream>>>(
        hvcat, fwT, nullptr, nullptr, ybuf, N, 768, 256, 0, 0, 0, 0);
    gemm_bf16<0, 1><<<dim3(2, (N + 127) / 128, 1), 256, 0, stream>>>(
        ybuf, fcT, nullptr, fcb, xh256, N, 256, 256, 0, 0, 0, 0);

    // ---- fusion-graph GCN (graph 3; self loops in epilogue) ----
    const int* rpF = rp4 + 3 * (N + 1);
    const int* colF = col4 + (size_t)3 * E;
    gemm_bf16<1, 0><<<dim3(2, (N + 127) / 128, 1), 256, 0, stream>>>(
        xh256, wm0T, norms + 6 * N, nullptr, m256, N, 256, 256, 0, 0, 0, 0);
    spmm_bf16<256, 1, 1, 0><<<dim3((N + 7) / 8, 1), 256, 0, stream>>>(
        rpF, colF, m256, norms + 6 * N, bm0, bm0, bm0, xh1, nullptr,
        N, E, 0, 0, 0, 256, 0);
    gemm_bf16<1, 0><<<dim3(1, (N + 127) / 128, 1), 256, 0, stream>>>(
        xh1, wm1T, norms + 6 * N, nullptr, h128, N, 256, 128, 0, 0, 0, 0);
    float* xhf = out + (size_t)3 * N * N;
    spmm_bf16<128, 0, 1, 1><<<dim3((N + 15) / 16, 1), 256, 0, stream>>>(
        rpF, colF, h128, norms + 6 * N, bm1, bm1, bm1, xb, xhf,
        N, E, 0, 0, 0, 128, 0);

    // ---- decoder ----
    gemm_bf16<0, 0><<<dim3(1, (N + 127) / 128, 1), 256, 0, stream>>>(
        xb, decT, nullptr, nullptr, zb, N, 128, 128, 0, 0, 0, 0);
    dim3 agrid((N + 127) / 128, (N + 127) / 128);
    adj_mfma<<<agrid, 256, 0, stream>>>(zb, xb, out, N);
}

// Round 5
// 895.220 us; speedup vs baseline: 2.9023x; 1.0100x over previous
//
#include <hip/hip_runtime.h>
#include <hip/hip_bf16.h>
#include <cstdint>
#include <cstddef>

typedef __attribute__((ext_vector_type(8))) short s16x8;   // 8 bf16 in 4 VGPRs
typedef __attribute__((ext_vector_type(4))) float f32x4;

// ---------------- helpers ----------------

__device__ inline float sigmoidf_fast(float x) {
    return 1.0f / (1.0f + __expf(-x));
}

__device__ inline ushort f2bf_bits(float x) {
    __hip_bfloat16 h = __float2bfloat16(x);
    return *reinterpret_cast<ushort*>(&h);
}

__device__ inline uint pk2bf(float a, float b) {
    return (uint)f2bf_bits(a) | ((uint)f2bf_bits(b) << 16);
}

// ---------------- fused prep: zero counters + weight transposes + T1=fc@wm0 ----------------

struct PrepArgs {
    int4* zeroPtr; int nZero4;                 // counter zeroing
    const float* tsrc[8]; ushort* tdst[8];     // transpose jobs: dst[n*ld+k] = src[k*NC+n]
    int tK[8], tNC[8], tld[8];
    int tBase[9];                              // cumulative block bases (W range)
    const float* fc; const float* wm0; const float* fcb;
    float* T1;                                 // [257][256]: rows 0..255 = fc@wm0, row 256 = fcb@wm0
    int zBlocks, wBlocks, tBlocks;
};

__global__ __launch_bounds__(256) void prep_misc(PrepArgs a) {
    int b = blockIdx.x;
    int tid = threadIdx.x;
    if (b < a.zBlocks) {
        int i = b * 256 + tid;
        if (i < a.nZero4) a.zeroPtr[i] = make_int4(0, 0, 0, 0);
        return;
    }
    b -= a.zBlocks;
    if (b < a.wBlocks) {
        int j = 0;
        while (!(b >= a.tBase[j] && b < a.tBase[j + 1])) ++j;
        int e = (b - a.tBase[j]) * 256 + tid;
        int K = a.tK[j], NC = a.tNC[j];
        if (e < K * NC) {
            int k = e / NC, n = e - k * NC;
            a.tdst[j][(size_t)n * a.tld[j] + k] = f2bf_bits(a.tsrc[j][e]);
        }
        return;
    }
    b -= a.wBlocks;
    // T1 range: block b = row j (0..256), thread = col n
    int n = tid;
    float accv = 0.f;
    if (b < 256) {
        const float* fr = a.fc + (size_t)b * 256;
        for (int i = 0; i < 256; ++i) accv += fr[i] * a.wm0[(size_t)i * 256 + n];
        a.T1[(size_t)b * 256 + n] = accv;
    } else {
        for (int i = 0; i < 256; ++i) accv += a.fcb[i] * a.wm0[(size_t)i * 256 + n];
        a.T1[(size_t)256 * 256 + n] = accv;
    }
}

// W_effT[n][k] = sum_j Fw_cat[k][j] * T1[j][n]  (Fw_cat = [fw1;fw2;fw3], 768x256)
__global__ __launch_bounds__(256) void weff_main(
    const float* __restrict__ fw0, const float* __restrict__ fw1, const float* __restrict__ fw2,
    const float* __restrict__ T1, ushort* __restrict__ weffT)
{
    int k = blockIdx.x;         // 0..767
    int n = threadIdx.x;        // 0..255
    const float* src = (k < 256 ? fw0 : (k < 512 ? fw1 : fw2)) + (size_t)(k & 255) * 256;
    float a = 0.f;
    for (int j = 0; j < 256; ++j) a += src[j] * T1[(size_t)j * 256 + n];
    weffT[(size_t)n * 768 + k] = f2bf_bits(a);
}

// ---------------- batched feature convert ----------------

__global__ void f2bf3(const float* __restrict__ s0, const float* __restrict__ s1,
                      const float* __restrict__ s2, ushort* __restrict__ dst, int n4) {
    int z = blockIdx.y;
    const float* src = z == 0 ? s0 : (z == 1 ? s1 : s2);
    int i = blockIdx.x * 256 + threadIdx.x;
    if (i < n4) {
        float4 v = ((const float4*)src)[i];
        uint2 o;
        o.x = pk2bf(v.x, v.y);
        o.y = pk2bf(v.z, v.w);
        ((uint2*)(dst + (size_t)z * n4 * 4))[i] = o;
    }
}

// ---------------- one-pass degree counts for all 4 graphs ----------------

__global__ void count_all(const int* __restrict__ s0, const int* __restrict__ d0,
                          const int* __restrict__ s1, const int* __restrict__ d1,
                          const int* __restrict__ s2, const int* __restrict__ d2,
                          const int* __restrict__ s3, const int* __restrict__ d3,
                          int* __restrict__ cntOut, int* __restrict__ cntIn, int E, int N) {
    int i = blockIdx.x * 256 + threadIdx.x;
    if (i >= E) return;
    atomicAdd(&cntOut[s0[i]], 1);          atomicAdd(&cntIn[d0[i]], 1);
    atomicAdd(&cntOut[N + s1[i]], 1);      atomicAdd(&cntIn[N + d1[i]], 1);
    atomicAdd(&cntOut[2 * N + s2[i]], 1);  atomicAdd(&cntIn[2 * N + d2[i]], 1);
    atomicAdd(&cntOut[3 * N + s3[i]], 1);  atomicAdd(&cntIn[3 * N + d3[i]], 1);
}

// ---------------- CSR scan (4 graphs, 1 block each) + norms fused ----------------

__global__ void scan4norm(const int* __restrict__ cntOut, const int* __restrict__ cntIn,
                          int* __restrict__ rp4, float* __restrict__ norms, int N) {
    __shared__ int partial[1024];
    int g = blockIdx.x;
    const int* counts = cntIn + (size_t)g * N;
    int* rowptr = rp4 + (size_t)g * (N + 1);
    int tid = threadIdx.x;

    // norms for graph g (out then in halves); fusion graph (g=3) has +1 self loop
    int add = (g == 3) ? 1 : 0;
    for (int idx = tid; idx < 2 * N; idx += 1024) {
        int c = (idx < N) ? (cntOut[g * N + idx] + add) : (cntIn[g * N + idx - N] + add);
        norms[(size_t)g * 2 * N + idx] = c > 0 ? rsqrtf((float)c) : 0.0f;
    }

    int per = (N + 1023) >> 10;
    int start = tid * per;
    int s = 0;
    for (int i = 0; i < per; ++i) {
        int idx = start + i;
        if (idx < N) s += counts[idx];
    }
    partial[tid] = s;
    __syncthreads();
    for (int off = 1; off < 1024; off <<= 1) {
        int v = (tid >= off) ? partial[tid - off] : 0;
        __syncthreads();
        partial[tid] += v;
        __syncthreads();
    }
    int run = (tid > 0) ? partial[tid - 1] : 0;
    for (int i = 0; i < per; ++i) {
        int idx = start + i;
        if (idx < N) { rowptr[idx] = run; run += counts[idx]; }
    }
    if (tid == 1023) rowptr[N] = partial[1023];
}

__global__ void scatter4(const int* __restrict__ s0, const int* __restrict__ d0,
                         const int* __restrict__ s1, const int* __restrict__ d1,
                         const int* __restrict__ s2, const int* __restrict__ d2,
                         const int* __restrict__ s3, const int* __restrict__ d3,
                         const int* __restrict__ rp4, int* __restrict__ cursor4,
                         int* __restrict__ col4, int E, int N) {
    int g = blockIdx.y;
    const int* ss[4] = { s0, s1, s2, s3 };
    const int* dd[4] = { d0, d1, d2, d3 };
    int i = blockIdx.x * 256 + threadIdx.x;
    if (i >= E) return;
    int d = dd[g][i];
    int pos = atomicAdd(&cursor4[g * N + d], 1);
    col4[(size_t)g * E + rp4[(size_t)g * (N + 1) + d] + pos] = ss[g][i];
}

// ---------------- bf16 MFMA GEMM (batched via grid.z) ----------------
// POST=0: C = acc*scale + bias ; POST=1: C = (acc + bias)*scale
// BT is B transposed [NC,K]. 128x128 tile, 4 waves, 16x16x32 MFMA, XOR-swizzled LDS.

template<int HAS_SCALE, int HAS_BIAS, int POST>
__global__ __launch_bounds__(256) void gemm_bf16(
    const ushort* __restrict__ A, const ushort* __restrict__ BT,
    const float* __restrict__ rowscale, const float* __restrict__ bias,
    ushort* __restrict__ C, int M, int K, int NC,
    size_t aStride, size_t btStride, size_t cStride, int sStride)
{
    int v = blockIdx.z;
    A += (size_t)v * aStride;
    BT += (size_t)v * btStride;
    C += (size_t)v * cStride;
    if (HAS_SCALE) rowscale += (size_t)v * sStride;

    __shared__ ushort As[128 * 64];
    __shared__ ushort Bs[128 * 64];
    int tid = threadIdx.x;
    int wave = tid >> 6, lane = tid & 63;
    int wr = wave >> 1, wc = wave & 1;
    int rowBase = blockIdx.y * 128, colBase = blockIdx.x * 128;
    int lr = lane & 15, kg = lane >> 4;

    f32x4 acc[4][4] = {};

    for (int k0 = 0; k0 < K; k0 += 64) {
#pragma unroll
        for (int i = 0; i < 4; ++i) {
            int id = i * 256 + tid;
            int row = id >> 3;
            int co  = (id & 7) << 3;
            int boff = ((row * 64 + co) << 1) ^ ((row & 7) << 4);
            int ar = rowBase + row; if (ar >= M) ar = M - 1;
            uint4 av = *(const uint4*)(A + (size_t)ar * K + k0 + co);
            *(uint4*)((char*)As + boff) = av;
            int bc = colBase + row;
            uint4 bv = *(const uint4*)(BT + (size_t)bc * K + k0 + co);
            *(uint4*)((char*)Bs + boff) = bv;
        }
        __syncthreads();
#pragma unroll
        for (int ks = 0; ks < 2; ++ks) {
            s16x8 afr[4], bfr[4];
#pragma unroll
            for (int m = 0; m < 4; ++m) {
                int fr = wr * 64 + m * 16 + lr;
                int boff = ((fr * 64 + ks * 32 + kg * 8) << 1) ^ ((fr & 7) << 4);
                afr[m] = *(const s16x8*)((char*)As + boff);
            }
#pragma unroll
            for (int n = 0; n < 4; ++n) {
                int fc = wc * 64 + n * 16 + lr;
                int boff = ((fc * 64 + ks * 32 + kg * 8) << 1) ^ ((fc & 7) << 4);
                bfr[n] = *(const s16x8*)((char*)Bs + boff);
            }
#pragma unroll
            for (int m = 0; m < 4; ++m)
#pragma unroll
                for (int n = 0; n < 4; ++n)
                    acc[m][n] = __builtin_amdgcn_mfma_f32_16x16x32_bf16(afr[m], bfr[n], acc[m][n], 0, 0, 0);
        }
        __syncthreads();
    }

#pragma unroll
    for (int m = 0; m < 4; ++m) {
#pragma unroll
        for (int i = 0; i < 4; ++i) {
            int r = rowBase + wr * 64 + m * 16 + kg * 4 + i;
            if (r >= M) continue;
            float s = HAS_SCALE ? rowscale[r] : 1.0f;
#pragma unroll
            for (int n = 0; n < 4; ++n) {
                int c = colBase + wc * 64 + n * 16 + lr;
                float vv = acc[m][n][i];
                if (POST) {
                    vv = (vv + (HAS_BIAS ? bias[c] : 0.0f)) * s;
                } else {
                    vv *= s;
                    if (HAS_BIAS) vv += bias[c];
                }
                C[(size_t)r * NC + c] = f2bf_bits(vv);
            }
        }
    }
}

// ---------------- fused gather SpMM (bf16 in, fp32 accum), batched via grid.y ----------------

#define ACC8(u) { acc[0]+=__uint_as_float(u.x<<16); acc[1]+=__uint_as_float(u.x&0xffff0000u); \
                  acc[2]+=__uint_as_float(u.y<<16); acc[3]+=__uint_as_float(u.y&0xffff0000u); \
                  acc[4]+=__uint_as_float(u.z<<16); acc[5]+=__uint_as_float(u.z&0xffff0000u); \
                  acc[6]+=__uint_as_float(u.w<<16); acc[7]+=__uint_as_float(u.w&0xffff0000u); }

template<int W, int RELU, int SELF, int OUTF32>
__global__ __launch_bounds__(256) void spmm_bf16(
    const int* __restrict__ rp4, const int* __restrict__ col4,
    const ushort* __restrict__ hB, const float* __restrict__ normB,
    const float* __restrict__ b0v, const float* __restrict__ b1v, const float* __restrict__ b2v,
    ushort* __restrict__ outB, float* __restrict__ outf,
    int M, int E, size_t hStride, int ninStride, size_t outStride, int ldOut, int colOffPerV)
{
    constexpr int TPR = W / 8;
    constexpr int RPB = 256 / TPR;
    int v = blockIdx.y;
    const int* rowptr = rp4 + (size_t)v * (M + 1);
    const int* col = col4 + (size_t)v * E;
    const ushort* h = hB + (size_t)v * hStride;
    const float* n_in = normB + (size_t)v * ninStride + M;
    const float* bias = (v == 0) ? b0v : (v == 1 ? b1v : b2v);
    ushort* outb = outB + (size_t)v * outStride;
    int cOff = colOffPerV * v;

    int lpr = threadIdx.x & (TPR - 1);
    int r = blockIdx.x * RPB + (threadIdx.x / TPR);
    if (r >= M) return;
    int c = lpr * 8;

    float acc[8] = {};
    int beg = rowptr[r], end = rowptr[r + 1];
    int j = beg;
    for (; j + 3 < end; j += 4) {
        int sA = col[j], sB = col[j + 1], sC = col[j + 2], sD = col[j + 3];
        uint4 uA = *(const uint4*)(h + (size_t)sA * W + c);
        uint4 uB = *(const uint4*)(h + (size_t)sB * W + c);
        uint4 uC = *(const uint4*)(h + (size_t)sC * W + c);
        uint4 uD = *(const uint4*)(h + (size_t)sD * W + c);
        ACC8(uA); ACC8(uB); ACC8(uC); ACC8(uD);
    }
    for (; j < end; ++j) {
        int s = col[j];
        uint4 u = *(const uint4*)(h + (size_t)s * W + c);
        ACC8(u);
    }
    if (SELF) {
        uint4 u = *(const uint4*)(h + (size_t)r * W + c);
        ACC8(u);
    }
    float ni = n_in[r];
    float o[8];
    float4 bb0 = *(const float4*)(bias + c);
    float4 bb1 = *(const float4*)(bias + c + 4);
    o[0] = acc[0] * ni + bb0.x; o[1] = acc[1] * ni + bb0.y;
    o[2] = acc[2] * ni + bb0.z; o[3] = acc[3] * ni + bb0.w;
    o[4] = acc[4] * ni + bb1.x; o[5] = acc[5] * ni + bb1.y;
    o[6] = acc[6] * ni + bb1.z; o[7] = acc[7] * ni + bb1.w;
    if (RELU) {
#pragma unroll
        for (int q = 0; q < 8; ++q) o[q] = fmaxf(o[q], 0.f);
    }
    uint4 ob;
    ob.x = pk2bf(o[0], o[1]); ob.y = pk2bf(o[2], o[3]);
    ob.z = pk2bf(o[4], o[5]); ob.w = pk2bf(o[6], o[7]);
    *(uint4*)(outb + (size_t)r * ldOut + cOff + c) = ob;
    if (OUTF32) {
        *(float4*)(outf + (size_t)r * W + c) = make_float4(o[0], o[1], o[2], o[3]);
        *(float4*)(outf + (size_t)r * W + c + 4) = make_float4(o[4], o[5], o[6], o[7]);
    }
}

// ---------------- decoder: bf16 MFMA, out[r,c] = sigmoid(dot(Z[r],X[c])), K=128 ----------------

__global__ __launch_bounds__(256) void adj_mfma(
    const ushort* __restrict__ Zb, const ushort* __restrict__ Xb,
    float* __restrict__ out, int M)
{
    int wave = threadIdx.x >> 6;
    int lane = threadIdx.x & 63;
    int wr = wave >> 1, wc = wave & 1;
    int rowBase = blockIdx.y * 128 + wr * 64;
    int colBase = blockIdx.x * 128 + wc * 64;
    int lr = lane & 15;
    int kg = lane >> 4;

    f32x4 acc[4][4] = {};

    int ar[4], bc[4];
#pragma unroll
    for (int m = 0; m < 4; ++m) {
        int r = rowBase + m * 16 + lr; ar[m] = (r < M) ? r : (M - 1);
        int c = colBase + m * 16 + lr; bc[m] = (c < M) ? c : (M - 1);
    }

#pragma unroll
    for (int ks = 0; ks < 4; ++ks) {
        s16x8 afr[4], bfr[4];
#pragma unroll
        for (int m = 0; m < 4; ++m)
            afr[m] = *(const s16x8*)(Zb + (size_t)ar[m] * 128 + ks * 32 + kg * 8);
#pragma unroll
        for (int n = 0; n < 4; ++n)
            bfr[n] = *(const s16x8*)(Xb + (size_t)bc[n] * 128 + ks * 32 + kg * 8);
#pragma unroll
        for (int m = 0; m < 4; ++m)
#pragma unroll
            for (int n = 0; n < 4; ++n)
                acc[m][n] = __builtin_amdgcn_mfma_f32_16x16x32_bf16(afr[m], bfr[n], acc[m][n], 0, 0, 0);
    }

    size_t NN = (size_t)M * M;
#pragma unroll
    for (int m = 0; m < 4; ++m) {
#pragma unroll
        for (int i = 0; i < 4; ++i) {
            int r = rowBase + m * 16 + kg * 4 + i;
            if (r >= M) continue;
            float* rowp = out + (size_t)r * M;
#pragma unroll
            for (int n = 0; n < 4; ++n) {
                int c = colBase + n * 16 + lr;
                if (c >= M) continue;
                float v = sigmoidf_fast(acc[m][n][i]);
                __builtin_nontemporal_store(v, rowp + c);
                __builtin_nontemporal_store(v, rowp + c + NN);
                __builtin_nontemporal_store(v, rowp + c + 2 * NN);
            }
        }
    }
}

// ---------------- launcher ----------------

extern "C" void kernel_launch(void* const* d_in, const int* in_sizes, int n_in,
                              void* d_out, int out_size, void* d_ws, size_t ws_size,
                              hipStream_t stream)
{
    const int N = in_sizes[0] / 512;   // 10000
    const int E = in_sizes[3];         // 320000

    const float* feat[3] = { (const float*)d_in[0], (const float*)d_in[1], (const float*)d_in[2] };
    const int* gsrc[4] = { (const int*)d_in[3], (const int*)d_in[5], (const int*)d_in[7], (const int*)d_in[9] };
    const int* gdst[4] = { (const int*)d_in[4], (const int*)d_in[6], (const int*)d_in[8], (const int*)d_in[10] };
    const float* W0[3] = { (const float*)d_in[11], (const float*)d_in[15], (const float*)d_in[19] };
    const float* B0[3] = { (const float*)d_in[12], (const float*)d_in[16], (const float*)d_in[20] };
    const float* W1[3] = { (const float*)d_in[13], (const float*)d_in[17], (const float*)d_in[21] };
    const float* B1[3] = { (const float*)d_in[14], (const float*)d_in[18], (const float*)d_in[22] };
    const float* fw[3] = { (const float*)d_in[23], (const float*)d_in[24], (const float*)d_in[25] };
    const float* fcw = (const float*)d_in[26];
    const float* fcb = (const float*)d_in[27];
    const float* wm0 = (const float*)d_in[28];
    const float* bm0 = (const float*)d_in[29];
    const float* wm1 = (const float*)d_in[30];
    const float* bm1 = (const float*)d_in[31];
    const float* decw = (const float*)d_in[32];
    float* out = (float*)d_out;

    // ---- workspace layout ----
    uint8_t* p = (uint8_t*)d_ws;
    auto alloc = [&](size_t bytes) { void* r = p; p += (bytes + 255) & ~(size_t)255; return r; };

    float*  norms   = (float*)alloc((size_t)8 * N * 4);
    ushort* featb   = (ushort*)alloc((size_t)3 * N * 512 * 2);
    ushort* w0T     = (ushort*)alloc((size_t)3 * 512 * 512 * 2);
    ushort* w1T     = (ushort*)alloc((size_t)3 * 256 * 512 * 2);
    ushort* wm1T    = (ushort*)alloc((size_t)128 * 256 * 2);
    ushort* decT    = (ushort*)alloc((size_t)128 * 128 * 2);
    float*  T1f     = (float*)alloc((size_t)257 * 256 * 4);   // fc@wm0 + bias row
    ushort* weffT   = (ushort*)alloc((size_t)256 * 768 * 2);  // (Fw@fc@wm0)^T
    ushort* h512_3  = (ushort*)alloc((size_t)3 * N * 512 * 2);
    ushort* hb512_3 = (ushort*)alloc((size_t)3 * N * 512 * 2);
    ushort* h256_3  = (ushort*)alloc((size_t)3 * N * 256 * 2);
    ushort* hvcat   = (ushort*)alloc((size_t)N * 768 * 2);
    ushort* m256    = (ushort*)alloc((size_t)N * 256 * 2);
    ushort* xh1     = (ushort*)alloc((size_t)N * 256 * 2);
    ushort* h128    = (ushort*)alloc((size_t)N * 128 * 2);
    ushort* xb      = (ushort*)alloc((size_t)N * 128 * 2);
    ushort* zb      = (ushort*)alloc((size_t)N * 128 * 2);
    int* cntOut     = (int*)alloc((size_t)4 * N * 4);     // must stay contiguous:
    int* cntIn      = (int*)alloc((size_t)4 * N * 4);     //   cntOut | cntIn | cursor4
    int* cursor4    = (int*)alloc((size_t)4 * N * 4);
    int* rp4        = (int*)alloc((size_t)4 * (N + 1) * 4);
    int* col4       = (int*)alloc((size_t)4 * E * 4);

    // ---- prep: zero counters + weight transposes + T1 (one kernel) ----
    PrepArgs pa;
    pa.zeroPtr = (int4*)cntOut; pa.nZero4 = 12 * N / 4;
    int wb = 0;
    auto addJob = [&](int j, const float* s, ushort* d, int K, int NC, int ld) {
        pa.tsrc[j] = s; pa.tdst[j] = d; pa.tK[j] = K; pa.tNC[j] = NC; pa.tld[j] = ld;
        pa.tBase[j] = wb; wb += (K * NC + 255) / 256;
    };
    for (int v = 0; v < 3; ++v) addJob(v, W0[v], w0T + (size_t)v * 512 * 512, 512, 512, 512);
    for (int v = 0; v < 3; ++v) addJob(3 + v, W1[v], w1T + (size_t)v * 256 * 512, 512, 256, 512);
    addJob(6, wm1, wm1T, 256, 128, 256);
    addJob(7, decw, decT, 128, 128, 128);
    pa.tBase[8] = wb;
    pa.fc = fcw; pa.wm0 = wm0; pa.fcb = fcb; pa.T1 = T1f;
    pa.zBlocks = (pa.nZero4 + 255) / 256;
    pa.wBlocks = wb;
    pa.tBlocks = 257;
    prep_misc<<<pa.zBlocks + pa.wBlocks + pa.tBlocks, 256, 0, stream>>>(pa);

    // ---- feature convert + combined fusion weight ----
    f2bf3<<<dim3((N * 512 / 4 + 255) / 256, 3), 256, 0, stream>>>(feat[0], feat[1], feat[2], featb, N * 512 / 4);
    weff_main<<<768, 256, 0, stream>>>(fw[0], fw[1], fw[2], T1f, weffT);

    // ---- graph prep ----
    count_all<<<(E + 255) / 256, 256, 0, stream>>>(
        gsrc[0], gdst[0], gsrc[1], gdst[1], gsrc[2], gdst[2], gsrc[3], gdst[3], cntOut, cntIn, E, N);
    scan4norm<<<4, 1024, 0, stream>>>(cntOut, cntIn, rp4, norms, N);
    scatter4<<<dim3((E + 255) / 256, 4), 256, 0, stream>>>(
        gsrc[0], gdst[0], gsrc[1], gdst[1], gsrc[2], gdst[2], gsrc[3], gdst[3],
        rp4, cursor4, col4, E, N);

    // ---- per-view GCN stacks (batched over 3 views) ----
    gemm_bf16<1, 0, 0><<<dim3(4, (N + 127) / 128, 3), 256, 0, stream>>>(
        featb, w0T, norms, nullptr, h512_3, N, 512, 512,
        (size_t)N * 512, (size_t)512 * 512, (size_t)N * 512, 2 * N);
    spmm_bf16<512, 1, 0, 0><<<dim3((N + 3) / 4, 3), 256, 0, stream>>>(
        rp4, col4, h512_3, norms, B0[0], B0[1], B0[2], hb512_3, nullptr,
        N, E, (size_t)N * 512, 2 * N, (size_t)N * 512, 512, 0);
    gemm_bf16<1, 0, 0><<<dim3(2, (N + 127) / 128, 3), 256, 0, stream>>>(
        hb512_3, w1T, norms, nullptr, h256_3, N, 512, 256,
        (size_t)N * 512, (size_t)256 * 512, (size_t)N * 256, 2 * N);
    spmm_bf16<256, 0, 0, 0><<<dim3((N + 7) / 8, 3), 256, 0, stream>>>(
        rp4, col4, h256_3, norms, B1[0], B1[1], B1[2], hvcat, nullptr,
        N, E, (size_t)N * 256, 2 * N, 0, 768, 256);

    // ---- collapsed fusion + wm0: m256 = (hvcat @ W_eff + b_eff) * n_out ----
    gemm_bf16<1, 1, 1><<<dim3(2, (N + 127) / 128, 1), 256, 0, stream>>>(
        hvcat, weffT, norms + 6 * N, T1f + 256 * 256, m256, N, 768, 256, 0, 0, 0, 0);

    // ---- fusion-graph GCN (graph 3; self loops in epilogue) ----
    const int* rpF = rp4 + 3 * (N + 1);
    const int* colF = col4 + (size_t)3 * E;
    spmm_bf16<256, 1, 1, 0><<<dim3((N + 7) / 8, 1), 256, 0, stream>>>(
        rpF, colF, m256, norms + 6 * N, bm0, bm0, bm0, xh1, nullptr,
        N, E, 0, 0, 0, 256, 0);
    gemm_bf16<1, 0, 0><<<dim3(1, (N + 127) / 128, 1), 256, 0, stream>>>(
        xh1, wm1T, norms + 6 * N, nullptr, h128, N, 256, 128, 0, 0, 0, 0);
    float* xhf = out + (size_t)3 * N * N;
    spmm_bf16<128, 0, 1, 1><<<dim3((N + 15) / 16, 1), 256, 0, stream>>>(
        rpF, colF, h128, norms + 6 * N, bm1, bm1, bm1, xb, xhf,
        N, E, 0, 0, 0, 128, 0);

    // ---- decoder ----
    gemm_bf16<0, 0, 0><<<dim3(1, (N + 127) / 128, 1), 256, 0, stream>>>(
        xb, decT, nullptr, nullptr, zb, N, 128, 128, 0, 0, 0, 0);
    dim3 agrid((N + 127) / 128, (N + 127) / 128);
    adj_mfma<<<agrid, 256, 0, stream>>>(zb, xb, out, N);
}

// Round 6
// 882.656 us; speedup vs baseline: 2.9436x; 1.0142x over previous
//
#include <hip/hip_runtime.h>
#include <hip/hip_bf16.h>
#include <cstdint>
#include <cstddef>

typedef __attribute__((ext_vector_type(8))) short s16x8;   // 8 bf16 in 4 VGPRs
typedef __attribute__((ext_vector_type(4))) float f32x4;

// ---------------- helpers ----------------

__device__ inline float sigmoidf_fast(float x) {
    return 1.0f / (1.0f + __expf(-x));
}

__device__ inline ushort f2bf_bits(float x) {
    __hip_bfloat16 h = __float2bfloat16(x);
    return *reinterpret_cast<ushort*>(&h);
}

__device__ inline uint pk2bf(float a, float b) {
    return (uint)f2bf_bits(a) | ((uint)f2bf_bits(b) << 16);
}

// ---------------- fused prep: zero counters + weight transposes + T1=fc@wm0 ----------------

struct PrepArgs {
    int4* zeroPtr; int nZero4;                 // counter zeroing
    const float* tsrc[8]; ushort* tdst[8];     // transpose jobs: dst[n*ld+k] = src[k*NC+n]
    int tK[8], tNC[8], tld[8];
    int tBase[9];                              // cumulative block bases (W range)
    const float* fc; const float* wm0; const float* fcb;
    float* T1;                                 // [257][256]: rows 0..255 = fc@wm0, row 256 = fcb@wm0
    int zBlocks, wBlocks, tBlocks;
};

__global__ __launch_bounds__(256) void prep_misc(PrepArgs a) {
    int b = blockIdx.x;
    int tid = threadIdx.x;
    if (b < a.zBlocks) {
        int i = b * 256 + tid;
        if (i < a.nZero4) a.zeroPtr[i] = make_int4(0, 0, 0, 0);
        return;
    }
    b -= a.zBlocks;
    if (b < a.wBlocks) {
        int j = 0;
        while (!(b >= a.tBase[j] && b < a.tBase[j + 1])) ++j;
        int e = (b - a.tBase[j]) * 256 + tid;
        int K = a.tK[j], NC = a.tNC[j];
        if (e < K * NC) {
            int k = e / NC, n = e - k * NC;
            a.tdst[j][(size_t)n * a.tld[j] + k] = f2bf_bits(a.tsrc[j][e]);
        }
        return;
    }
    b -= a.wBlocks;
    // T1 range: block b = row j (0..256), thread = col n
    int n = tid;
    float accv = 0.f;
    if (b < 256) {
        const float* fr = a.fc + (size_t)b * 256;
        for (int i = 0; i < 256; ++i) accv += fr[i] * a.wm0[(size_t)i * 256 + n];
        a.T1[(size_t)b * 256 + n] = accv;
    } else {
        for (int i = 0; i < 256; ++i) accv += a.fcb[i] * a.wm0[(size_t)i * 256 + n];
        a.T1[(size_t)256 * 256 + n] = accv;
    }
}

// W_effT[n][k] = sum_j Fw_cat[k][j] * T1[j][n]  (Fw_cat = [fw1;fw2;fw3], 768x256)
__global__ __launch_bounds__(256) void weff_main(
    const float* __restrict__ fw0, const float* __restrict__ fw1, const float* __restrict__ fw2,
    const float* __restrict__ T1, ushort* __restrict__ weffT)
{
    int k = blockIdx.x;         // 0..767
    int n = threadIdx.x;        // 0..255
    const float* src = (k < 256 ? fw0 : (k < 512 ? fw1 : fw2)) + (size_t)(k & 255) * 256;
    float a = 0.f;
    for (int j = 0; j < 256; ++j) a += src[j] * T1[(size_t)j * 256 + n];
    weffT[(size_t)n * 768 + k] = f2bf_bits(a);
}

// ---------------- batched feature convert ----------------

__global__ void f2bf3(const float* __restrict__ s0, const float* __restrict__ s1,
                      const float* __restrict__ s2, ushort* __restrict__ dst, int n4) {
    int z = blockIdx.y;
    const float* src = z == 0 ? s0 : (z == 1 ? s1 : s2);
    int i = blockIdx.x * 256 + threadIdx.x;
    if (i < n4) {
        float4 v = ((const float4*)src)[i];
        uint2 o;
        o.x = pk2bf(v.x, v.y);
        o.y = pk2bf(v.z, v.w);
        ((uint2*)(dst + (size_t)z * n4 * 4))[i] = o;
    }
}

// ---------------- one-pass degree counts for all 4 graphs ----------------

__global__ void count_all(const int* __restrict__ s0, const int* __restrict__ d0,
                          const int* __restrict__ s1, const int* __restrict__ d1,
                          const int* __restrict__ s2, const int* __restrict__ d2,
                          const int* __restrict__ s3, const int* __restrict__ d3,
                          int* __restrict__ cntOut, int* __restrict__ cntIn, int E, int N) {
    int i = blockIdx.x * 256 + threadIdx.x;
    if (i >= E) return;
    atomicAdd(&cntOut[s0[i]], 1);          atomicAdd(&cntIn[d0[i]], 1);
    atomicAdd(&cntOut[N + s1[i]], 1);      atomicAdd(&cntIn[N + d1[i]], 1);
    atomicAdd(&cntOut[2 * N + s2[i]], 1);  atomicAdd(&cntIn[2 * N + d2[i]], 1);
    atomicAdd(&cntOut[3 * N + s3[i]], 1);  atomicAdd(&cntIn[3 * N + d3[i]], 1);
}

// ---------------- CSR scan (4 graphs, 1 block each) + norms fused ----------------

__global__ void scan4norm(const int* __restrict__ cntOut, const int* __restrict__ cntIn,
                          int* __restrict__ rp4, float* __restrict__ norms, int N) {
    __shared__ int partial[1024];
    int g = blockIdx.x;
    const int* counts = cntIn + (size_t)g * N;
    int* rowptr = rp4 + (size_t)g * (N + 1);
    int tid = threadIdx.x;

    // norms for graph g (out then in halves); fusion graph (g=3) has +1 self loop
    int add = (g == 3) ? 1 : 0;
    for (int idx = tid; idx < 2 * N; idx += 1024) {
        int c = (idx < N) ? (cntOut[g * N + idx] + add) : (cntIn[g * N + idx - N] + add);
        norms[(size_t)g * 2 * N + idx] = c > 0 ? rsqrtf((float)c) : 0.0f;
    }

    int per = (N + 1023) >> 10;
    int start = tid * per;
    int s = 0;
    for (int i = 0; i < per; ++i) {
        int idx = start + i;
        if (idx < N) s += counts[idx];
    }
    partial[tid] = s;
    __syncthreads();
    for (int off = 1; off < 1024; off <<= 1) {
        int v = (tid >= off) ? partial[tid - off] : 0;
        __syncthreads();
        partial[tid] += v;
        __syncthreads();
    }
    int run = (tid > 0) ? partial[tid - 1] : 0;
    for (int i = 0; i < per; ++i) {
        int idx = start + i;
        if (idx < N) { rowptr[idx] = run; run += counts[idx]; }
    }
    if (tid == 1023) rowptr[N] = partial[1023];
}

__global__ void scatter4(const int* __restrict__ s0, const int* __restrict__ d0,
                         const int* __restrict__ s1, const int* __restrict__ d1,
                         const int* __restrict__ s2, const int* __restrict__ d2,
                         const int* __restrict__ s3, const int* __restrict__ d3,
                         const int* __restrict__ rp4, int* __restrict__ cursor4,
                         int* __restrict__ col4, int E, int N) {
    int g = blockIdx.y;
    const int* ss[4] = { s0, s1, s2, s3 };
    const int* dd[4] = { d0, d1, d2, d3 };
    int i = blockIdx.x * 256 + threadIdx.x;
    if (i >= E) return;
    int d = dd[g][i];
    int pos = atomicAdd(&cursor4[g * N + d], 1);
    col4[(size_t)g * E + rp4[(size_t)g * (N + 1) + d] + pos] = ss[g][i];
}

// ---------------- bf16 MFMA GEMM (batched via grid.z) ----------------
// POST=0: C = acc*scale + bias ; POST=1: C = (acc + bias)*scale
// BT is B transposed [NC,K]. 128x128 tile, 4 waves, 16x16x32 MFMA, XOR-swizzled LDS.

template<int HAS_SCALE, int HAS_BIAS, int POST>
__global__ __launch_bounds__(256) void gemm_bf16(
    const ushort* __restrict__ A, const ushort* __restrict__ BT,
    const float* __restrict__ rowscale, const float* __restrict__ bias,
    ushort* __restrict__ C, int M, int K, int NC,
    size_t aStride, size_t btStride, size_t cStride, int sStride)
{
    int v = blockIdx.z;
    A += (size_t)v * aStride;
    BT += (size_t)v * btStride;
    C += (size_t)v * cStride;
    if (HAS_SCALE) rowscale += (size_t)v * sStride;

    __shared__ ushort As[128 * 64];
    __shared__ ushort Bs[128 * 64];
    int tid = threadIdx.x;
    int wave = tid >> 6, lane = tid & 63;
    int wr = wave >> 1, wc = wave & 1;
    int rowBase = blockIdx.y * 128, colBase = blockIdx.x * 128;
    int lr = lane & 15, kg = lane >> 4;

    f32x4 acc[4][4] = {};

    for (int k0 = 0; k0 < K; k0 += 64) {
#pragma unroll
        for (int i = 0; i < 4; ++i) {
            int id = i * 256 + tid;
            int row = id >> 3;
            int co  = (id & 7) << 3;
            int boff = ((row * 64 + co) << 1) ^ ((row & 7) << 4);
            int ar = rowBase + row; if (ar >= M) ar = M - 1;
            uint4 av = *(const uint4*)(A + (size_t)ar * K + k0 + co);
            *(uint4*)((char*)As + boff) = av;
            int bc = colBase + row;
            uint4 bv = *(const uint4*)(BT + (size_t)bc * K + k0 + co);
            *(uint4*)((char*)Bs + boff) = bv;
        }
        __syncthreads();
#pragma unroll
        for (int ks = 0; ks < 2; ++ks) {
            s16x8 afr[4], bfr[4];
#pragma unroll
            for (int m = 0; m < 4; ++m) {
                int fr = wr * 64 + m * 16 + lr;
                int boff = ((fr * 64 + ks * 32 + kg * 8) << 1) ^ ((fr & 7) << 4);
                afr[m] = *(const s16x8*)((char*)As + boff);
            }
#pragma unroll
            for (int n = 0; n < 4; ++n) {
                int fc = wc * 64 + n * 16 + lr;
                int boff = ((fc * 64 + ks * 32 + kg * 8) << 1) ^ ((fc & 7) << 4);
                bfr[n] = *(const s16x8*)((char*)Bs + boff);
            }
#pragma unroll
            for (int m = 0; m < 4; ++m)
#pragma unroll
                for (int n = 0; n < 4; ++n)
                    acc[m][n] = __builtin_amdgcn_mfma_f32_16x16x32_bf16(afr[m], bfr[n], acc[m][n], 0, 0, 0);
        }
        __syncthreads();
    }

#pragma unroll
    for (int m = 0; m < 4; ++m) {
#pragma unroll
        for (int i = 0; i < 4; ++i) {
            int r = rowBase + wr * 64 + m * 16 + kg * 4 + i;
            if (r >= M) continue;
            float s = HAS_SCALE ? rowscale[r] : 1.0f;
#pragma unroll
            for (int n = 0; n < 4; ++n) {
                int c = colBase + wc * 64 + n * 16 + lr;
                float vv = acc[m][n][i];
                if (POST) {
                    vv = (vv + (HAS_BIAS ? bias[c] : 0.0f)) * s;
                } else {
                    vv *= s;
                    if (HAS_BIAS) vv += bias[c];
                }
                C[(size_t)r * NC + c] = f2bf_bits(vv);
            }
        }
    }
}

// ---------------- fused gather SpMM (bf16 in, fp32 accum), batched via grid.y ----------------

#define ACC8(u) { acc[0]+=__uint_as_float(u.x<<16); acc[1]+=__uint_as_float(u.x&0xffff0000u); \
                  acc[2]+=__uint_as_float(u.y<<16); acc[3]+=__uint_as_float(u.y&0xffff0000u); \
                  acc[4]+=__uint_as_float(u.z<<16); acc[5]+=__uint_as_float(u.z&0xffff0000u); \
                  acc[6]+=__uint_as_float(u.w<<16); acc[7]+=__uint_as_float(u.w&0xffff0000u); }

template<int W, int RELU, int SELF, int OUTF32>
__global__ __launch_bounds__(256) void spmm_bf16(
    const int* __restrict__ rp4, const int* __restrict__ col4,
    const ushort* __restrict__ hB, const float* __restrict__ normB,
    const float* __restrict__ b0v, const float* __restrict__ b1v, const float* __restrict__ b2v,
    ushort* __restrict__ outB, float* __restrict__ outf,
    int M, int E, size_t hStride, int ninStride, size_t outStride, int ldOut, int colOffPerV)
{
    constexpr int TPR = W / 8;
    constexpr int RPB = 256 / TPR;
    int v = blockIdx.y;
    const int* rowptr = rp4 + (size_t)v * (M + 1);
    const int* col = col4 + (size_t)v * E;
    const ushort* h = hB + (size_t)v * hStride;
    const float* n_in = normB + (size_t)v * ninStride + M;
    const float* bias = (v == 0) ? b0v : (v == 1 ? b1v : b2v);
    ushort* outb = outB + (size_t)v * outStride;
    int cOff = colOffPerV * v;

    int lpr = threadIdx.x & (TPR - 1);
    int r = blockIdx.x * RPB + (threadIdx.x / TPR);
    if (r >= M) return;
    int c = lpr * 8;

    float acc[8] = {};
    int beg = rowptr[r], end = rowptr[r + 1];
    int j = beg;
    for (; j + 7 < end; j += 8) {
        int sA = col[j], sB = col[j + 1], sC = col[j + 2], sD = col[j + 3];
        int sE = col[j + 4], sF = col[j + 5], sG = col[j + 6], sH = col[j + 7];
        uint4 uA = *(const uint4*)(h + (size_t)sA * W + c);
        uint4 uB = *(const uint4*)(h + (size_t)sB * W + c);
        uint4 uC = *(const uint4*)(h + (size_t)sC * W + c);
        uint4 uD = *(const uint4*)(h + (size_t)sD * W + c);
        uint4 uE = *(const uint4*)(h + (size_t)sE * W + c);
        uint4 uF = *(const uint4*)(h + (size_t)sF * W + c);
        uint4 uG = *(const uint4*)(h + (size_t)sG * W + c);
        uint4 uH = *(const uint4*)(h + (size_t)sH * W + c);
        ACC8(uA); ACC8(uB); ACC8(uC); ACC8(uD);
        ACC8(uE); ACC8(uF); ACC8(uG); ACC8(uH);
    }
    for (; j + 3 < end; j += 4) {
        int sA = col[j], sB = col[j + 1], sC = col[j + 2], sD = col[j + 3];
        uint4 uA = *(const uint4*)(h + (size_t)sA * W + c);
        uint4 uB = *(const uint4*)(h + (size_t)sB * W + c);
        uint4 uC = *(const uint4*)(h + (size_t)sC * W + c);
        uint4 uD = *(const uint4*)(h + (size_t)sD * W + c);
        ACC8(uA); ACC8(uB); ACC8(uC); ACC8(uD);
    }
    for (; j < end; ++j) {
        int s = col[j];
        uint4 u = *(const uint4*)(h + (size_t)s * W + c);
        ACC8(u);
    }
    if (SELF) {
        uint4 u = *(const uint4*)(h + (size_t)r * W + c);
        ACC8(u);
    }
    float ni = n_in[r];
    float o[8];
    float4 bb0 = *(const float4*)(bias + c);
    float4 bb1 = *(const float4*)(bias + c + 4);
    o[0] = acc[0] * ni + bb0.x; o[1] = acc[1] * ni + bb0.y;
    o[2] = acc[2] * ni + bb0.z; o[3] = acc[3] * ni + bb0.w;
    o[4] = acc[4] * ni + bb1.x; o[5] = acc[5] * ni + bb1.y;
    o[6] = acc[6] * ni + bb1.z; o[7] = acc[7] * ni + bb1.w;
    if (RELU) {
#pragma unroll
        for (int q = 0; q < 8; ++q) o[q] = fmaxf(o[q], 0.f);
    }
    uint4 ob;
    ob.x = pk2bf(o[0], o[1]); ob.y = pk2bf(o[2], o[3]);
    ob.z = pk2bf(o[4], o[5]); ob.w = pk2bf(o[6], o[7]);
    *(uint4*)(outb + (size_t)r * ldOut + cOff + c) = ob;
    if (OUTF32) {
        *(float4*)(outf + (size_t)r * W + c) = make_float4(o[0], o[1], o[2], o[3]);
        *(float4*)(outf + (size_t)r * W + c + 4) = make_float4(o[4], o[5], o[6], o[7]);
    }
}

// ---------------- decoder: bf16 MFMA, out[r,c] = sigmoid(dot(Z[r],X[c])), K=128 ----------------
// Sigmoid applied in-register, then 3 per-plane store passes (stream-grouped for WC).

__global__ __launch_bounds__(256) void adj_mfma(
    const ushort* __restrict__ Zb, const ushort* __restrict__ Xb,
    float* __restrict__ out, int M)
{
    int wave = threadIdx.x >> 6;
    int lane = threadIdx.x & 63;
    int wr = wave >> 1, wc = wave & 1;
    int rowBase = blockIdx.y * 128 + wr * 64;
    int colBase = blockIdx.x * 128 + wc * 64;
    int lr = lane & 15;
    int kg = lane >> 4;

    f32x4 acc[4][4] = {};

    int ar[4], bc[4];
#pragma unroll
    for (int m = 0; m < 4; ++m) {
        int r = rowBase + m * 16 + lr; ar[m] = (r < M) ? r : (M - 1);
        int c = colBase + m * 16 + lr; bc[m] = (c < M) ? c : (M - 1);
    }

#pragma unroll
    for (int ks = 0; ks < 4; ++ks) {
        s16x8 afr[4], bfr[4];
#pragma unroll
        for (int m = 0; m < 4; ++m)
            afr[m] = *(const s16x8*)(Zb + (size_t)ar[m] * 128 + ks * 32 + kg * 8);
#pragma unroll
        for (int n = 0; n < 4; ++n)
            bfr[n] = *(const s16x8*)(Xb + (size_t)bc[n] * 128 + ks * 32 + kg * 8);
#pragma unroll
        for (int m = 0; m < 4; ++m)
#pragma unroll
            for (int n = 0; n < 4; ++n)
                acc[m][n] = __builtin_amdgcn_mfma_f32_16x16x32_bf16(afr[m], bfr[n], acc[m][n], 0, 0, 0);
    }

    // sigmoid all 64 values in-register
#pragma unroll
    for (int m = 0; m < 4; ++m)
#pragma unroll
        for (int n = 0; n < 4; ++n)
#pragma unroll
            for (int i = 0; i < 4; ++i)
                acc[m][n][i] = sigmoidf_fast(acc[m][n][i]);

    // 3 per-plane store passes (contiguous stream per pass)
    size_t NN = (size_t)M * M;
#pragma unroll
    for (int p = 0; p < 3; ++p) {
        float* base = out + (size_t)p * NN;
#pragma unroll
        for (int m = 0; m < 4; ++m) {
#pragma unroll
            for (int i = 0; i < 4; ++i) {
                int r = rowBase + m * 16 + kg * 4 + i;
                if (r >= M) continue;
                float* rowp = base + (size_t)r * M;
#pragma unroll
                for (int n = 0; n < 4; ++n) {
                    int c = colBase + n * 16 + lr;
                    if (c < M) __builtin_nontemporal_store(acc[m][n][i], rowp + c);
                }
            }
        }
    }
}

// ---------------- launcher ----------------

extern "C" void kernel_launch(void* const* d_in, const int* in_sizes, int n_in,
                              void* d_out, int out_size, void* d_ws, size_t ws_size,
                              hipStream_t stream)
{
    const int N = in_sizes[0] / 512;   // 10000
    const int E = in_sizes[3];         // 320000

    const float* feat[3] = { (const float*)d_in[0], (const float*)d_in[1], (const float*)d_in[2] };
    const int* gsrc[4] = { (const int*)d_in[3], (const int*)d_in[5], (const int*)d_in[7], (const int*)d_in[9] };
    const int* gdst[4] = { (const int*)d_in[4], (const int*)d_in[6], (const int*)d_in[8], (const int*)d_in[10] };
    const float* W0[3] = { (const float*)d_in[11], (const float*)d_in[15], (const float*)d_in[19] };
    const float* B0[3] = { (const float*)d_in[12], (const float*)d_in[16], (const float*)d_in[20] };
    const float* W1[3] = { (const float*)d_in[13], (const float*)d_in[17], (const float*)d_in[21] };
    const float* B1[3] = { (const float*)d_in[14], (const float*)d_in[18], (const float*)d_in[22] };
    const float* fw[3] = { (const float*)d_in[23], (const float*)d_in[24], (const float*)d_in[25] };
    const float* fcw = (const float*)d_in[26];
    const float* fcb = (const float*)d_in[27];
    const float* wm0 = (const float*)d_in[28];
    const float* bm0 = (const float*)d_in[29];
    const float* wm1 = (const float*)d_in[30];
    const float* bm1 = (const float*)d_in[31];
    const float* decw = (const float*)d_in[32];
    float* out = (float*)d_out;

    // ---- workspace layout ----
    uint8_t* p = (uint8_t*)d_ws;
    auto alloc = [&](size_t bytes) { void* r = p; p += (bytes + 255) & ~(size_t)255; return r; };

    float*  norms   = (float*)alloc((size_t)8 * N * 4);
    ushort* featb   = (ushort*)alloc((size_t)3 * N * 512 * 2);
    ushort* w0T     = (ushort*)alloc((size_t)3 * 512 * 512 * 2);
    ushort* w1T     = (ushort*)alloc((size_t)3 * 256 * 512 * 2);
    ushort* wm1T    = (ushort*)alloc((size_t)128 * 256 * 2);
    ushort* decT    = (ushort*)alloc((size_t)128 * 128 * 2);
    float*  T1f     = (float*)alloc((size_t)257 * 256 * 4);   // fc@wm0 + bias row
    ushort* weffT   = (ushort*)alloc((size_t)256 * 768 * 2);  // (Fw@fc@wm0)^T
    ushort* h512_3  = (ushort*)alloc((size_t)3 * N * 512 * 2);
    ushort* hb512_3 = (ushort*)alloc((size_t)3 * N * 512 * 2);
    ushort* h256_3  = (ushort*)alloc((size_t)3 * N * 256 * 2);
    ushort* hvcat   = (ushort*)alloc((size_t)N * 768 * 2);
    ushort* m256    = (ushort*)alloc((size_t)N * 256 * 2);
    ushort* xh1     = (ushort*)alloc((size_t)N * 256 * 2);
    ushort* h128    = (ushort*)alloc((size_t)N * 128 * 2);
    ushort* xb      = (ushort*)alloc((size_t)N * 128 * 2);
    ushort* zb      = (ushort*)alloc((size_t)N * 128 * 2);
    int* cntOut     = (int*)alloc((size_t)4 * N * 4);     // must stay contiguous:
    int* cntIn      = (int*)alloc((size_t)4 * N * 4);     //   cntOut | cntIn | cursor4
    int* cursor4    = (int*)alloc((size_t)4 * N * 4);
    int* rp4        = (int*)alloc((size_t)4 * (N + 1) * 4);
    int* col4       = (int*)alloc((size_t)4 * E * 4);

    // ---- prep: zero counters + weight transposes + T1 (one kernel) ----
    PrepArgs pa;
    pa.zeroPtr = (int4*)cntOut; pa.nZero4 = 12 * N / 4;
    int wb = 0;
    auto addJob = [&](int j, const float* s, ushort* d, int K, int NC, int ld) {
        pa.tsrc[j] = s; pa.tdst[j] = d; pa.tK[j] = K; pa.tNC[j] = NC; pa.tld[j] = ld;
        pa.tBase[j] = wb; wb += (K * NC + 255) / 256;
    };
    for (int v = 0; v < 3; ++v) addJob(v, W0[v], w0T + (size_t)v * 512 * 512, 512, 512, 512);
    for (int v = 0; v < 3; ++v) addJob(3 + v, W1[v], w1T + (size_t)v * 256 * 512, 512, 256, 512);
    addJob(6, wm1, wm1T, 256, 128, 256);
    addJob(7, decw, decT, 128, 128, 128);
    pa.tBase[8] = wb;
    pa.fc = fcw; pa.wm0 = wm0; pa.fcb = fcb; pa.T1 = T1f;
    pa.zBlocks = (pa.nZero4 + 255) / 256;
    pa.wBlocks = wb;
    pa.tBlocks = 257;
    prep_misc<<<pa.zBlocks + pa.wBlocks + pa.tBlocks, 256, 0, stream>>>(pa);

    // ---- feature convert + combined fusion weight ----
    f2bf3<<<dim3((N * 512 / 4 + 255) / 256, 3), 256, 0, stream>>>(feat[0], feat[1], feat[2], featb, N * 512 / 4);
    weff_main<<<768, 256, 0, stream>>>(fw[0], fw[1], fw[2], T1f, weffT);

    // ---- graph prep ----
    count_all<<<(E + 255) / 256, 256, 0, stream>>>(
        gsrc[0], gdst[0], gsrc[1], gdst[1], gsrc[2], gdst[2], gsrc[3], gdst[3], cntOut, cntIn, E, N);
    scan4norm<<<4, 1024, 0, stream>>>(cntOut, cntIn, rp4, norms, N);
    scatter4<<<dim3((E + 255) / 256, 4), 256, 0, stream>>>(
        gsrc[0], gdst[0], gsrc[1], gdst[1], gsrc[2], gdst[2], gsrc[3], gdst[3],
        rp4, cursor4, col4, E, N);

    // ---- per-view GCN stacks (batched over 3 views) ----
    gemm_bf16<1, 0, 0><<<dim3(4, (N + 127) / 128, 3), 256, 0, stream>>>(
        featb, w0T, norms, nullptr, h512_3, N, 512, 512,
        (size_t)N * 512, (size_t)512 * 512, (size_t)N * 512, 2 * N);
    spmm_bf16<512, 1, 0, 0><<<dim3((N + 3) / 4, 3), 256, 0, stream>>>(
        rp4, col4, h512_3, norms, B0[0], B0[1], B0[2], hb512_3, nullptr,
        N, E, (size_t)N * 512, 2 * N, (size_t)N * 512, 512, 0);
    gemm_bf16<1, 0, 0><<<dim3(2, (N + 127) / 128, 3), 256, 0, stream>>>(
        hb512_3, w1T, norms, nullptr, h256_3, N, 512, 256,
        (size_t)N * 512, (size_t)256 * 512, (size_t)N * 256, 2 * N);
    spmm_bf16<256, 0, 0, 0><<<dim3((N + 7) / 8, 3), 256, 0, stream>>>(
        rp4, col4, h256_3, norms, B1[0], B1[1], B1[2], hvcat, nullptr,
        N, E, (size_t)N * 256, 2 * N, 0, 768, 256);

    // ---- collapsed fusion + wm0: m256 = (hvcat @ W_eff + b_eff) * n_out ----
    gemm_bf16<1, 1, 1><<<dim3(2, (N + 127) / 128, 1), 256, 0, stream>>>(
        hvcat, weffT, norms + 6 * N, T1f + 256 * 256, m256, N, 768, 256, 0, 0, 0, 0);

    // ---- fusion-graph GCN (graph 3; self loops in epilogue) ----
    const int* rpF = rp4 + 3 * (N + 1);
    const int* colF = col4 + (size_t)3 * E;
    spmm_bf16<256, 1, 1, 0><<<dim3((N + 7) / 8, 1), 256, 0, stream>>>(
        rpF, colF, m256, norms + 6 * N, bm0, bm0, bm0, xh1, nullptr,
        N, E, 0, 0, 0, 256, 0);
    gemm_bf16<1, 0, 0><<<dim3(1, (N + 127) / 128, 1), 256, 0, stream>>>(
        xh1, wm1T, norms + 6 * N, nullptr, h128, N, 256, 128, 0, 0, 0, 0);
    float* xhf = out + (size_t)3 * N * N;
    spmm_bf16<128, 0, 1, 1><<<dim3((N + 15) / 16, 1), 256, 0, stream>>>(
        rpF, colF, h128, norms + 6 * N, bm1, bm1, bm1, xb, xhf,
        N, E, 0, 0, 0, 128, 0);

    // ---- decoder ----
    gemm_bf16<0, 0, 0><<<dim3(1, (N + 127) / 128, 1), 256, 0, stream>>>(
        xb, decT, nullptr, nullptr, zb, N, 128, 128, 0, 0, 0, 0);
    dim3 agrid((N + 127) / 128, (N + 127) / 128);
    adj_mfma<<<agrid, 256, 0, stream>>>(zb, xb, out, N);
}

// Round 7
// 871.652 us; speedup vs baseline: 2.9808x; 1.0126x over previous
//
#include <hip/hip_runtime.h>
#include <hip/hip_bf16.h>
#include <cstdint>
#include <cstddef>

typedef __attribute__((ext_vector_type(8))) short s16x8;   // 8 bf16 in 4 VGPRs
typedef __attribute__((ext_vector_type(4))) float f32x4;

// ---------------- helpers ----------------

__device__ inline float sigmoidf_fast(float x) {
    return 1.0f / (1.0f + __expf(-x));
}

__device__ inline ushort f2bf_bits(float x) {
    __hip_bfloat16 h = __float2bfloat16(x);
    return *reinterpret_cast<ushort*>(&h);
}

__device__ inline uint pk2bf(float a, float b) {
    return (uint)f2bf_bits(a) | ((uint)f2bf_bits(b) << 16);
}

// ---------------- fused prep: zero + LDS-tiled weight transposes + T1 + feature f2bf ----------------

struct PrepArgs {
    int4* zeroPtr; int nZero4;
    // transpose jobs (32x32 tiles): dst[n*ld + k] = bf16(src[k*NC + n])
    const float* tsrc[8]; ushort* tdst[8];
    int tNC[8], tld[8];
    int tTileBase[9];                          // cumulative tile bases
    const float* fc; const float* wm0; const float* fcb;
    float* T1;                                 // [257][256]: fc@wm0 ; row 256 = fcb@wm0
    const float* fsrc[3]; ushort* fdst; int fn4;   // feature convert (3 views)
    int zBlocks, tBlocks, t1Blocks;
};

__global__ __launch_bounds__(256) void prep_misc(PrepArgs a) {
    __shared__ float tile[32][33];
    int b = blockIdx.x;
    int tid = threadIdx.x;

    if (b < a.zBlocks) {                       // ---- zero counters ----
        int i = b * 256 + tid;
        if (i < a.nZero4) a.zeroPtr[i] = make_int4(0, 0, 0, 0);
        return;
    }
    b -= a.zBlocks;

    if (b < a.tBlocks) {                       // ---- LDS-tiled transpose ----
        int j = 0;
        while (b >= a.tTileBase[j + 1]) ++j;
        int t = b - a.tTileBase[j];
        int NC = a.tNC[j];
        int ntn = NC >> 5;
        int kb = t / ntn, nb = t - kb * ntn;
        const float* src = a.tsrc[j];
        int r = tid >> 5, c = tid & 31;
#pragma unroll
        for (int rr = 0; rr < 32; rr += 8)
            tile[r + rr][c] = src[(size_t)(kb * 32 + r + rr) * NC + nb * 32 + c];
        __syncthreads();
        int ld = a.tld[j];
        ushort* dst = a.tdst[j];
        int kp = tid & 15;                     // k-pair 0..15
        int r2 = tid >> 4;                     // 0..15 (+16 second pass)
#pragma unroll
        for (int pp = 0; pp < 2; ++pp) {
            int rn = r2 + pp * 16;
            int n = nb * 32 + rn;
            uint valu = pk2bf(tile[2 * kp][rn], tile[2 * kp + 1][rn]);
            *(uint*)(dst + (size_t)n * ld + kb * 32 + 2 * kp) = valu;
        }
        return;
    }
    b -= a.tBlocks;

    if (b < a.t1Blocks) {                      // ---- T1 = fc@wm0 (+ bias row) ----
        int n = tid;
        float accv = 0.f;
        if (b < 256) {
            const float* fr = a.fc + (size_t)b * 256;
            for (int i = 0; i < 256; ++i) accv += fr[i] * a.wm0[(size_t)i * 256 + n];
            a.T1[(size_t)b * 256 + n] = accv;
        } else {
            for (int i = 0; i < 256; ++i) accv += a.fcb[i] * a.wm0[(size_t)i * 256 + n];
            a.T1[(size_t)256 * 256 + n] = accv;
        }
        return;
    }
    b -= a.t1Blocks;

    // ---- feature fp32 -> bf16 (3 views) ----
    int perView = (a.fn4 + 255) / 256;
    int z = b / perView;
    int i = (b - z * perView) * 256 + tid;
    if (i < a.fn4) {
        float4 v = ((const float4*)a.fsrc[z])[i];
        uint2 o;
        o.x = pk2bf(v.x, v.y);
        o.y = pk2bf(v.z, v.w);
        ((uint2*)(a.fdst + (size_t)z * a.fn4 * 4))[i] = o;
    }
}

// W_effT[n][k] = sum_j Fw_cat[k][j] * T1[j][n]  (Fw_cat = [fw1;fw2;fw3], 768x256)
__global__ __launch_bounds__(256) void weff_main(
    const float* __restrict__ fw0, const float* __restrict__ fw1, const float* __restrict__ fw2,
    const float* __restrict__ T1, ushort* __restrict__ weffT)
{
    int k = blockIdx.x;         // 0..767
    int n = threadIdx.x;        // 0..255
    const float* src = (k < 256 ? fw0 : (k < 512 ? fw1 : fw2)) + (size_t)(k & 255) * 256;
    float a = 0.f;
    for (int j = 0; j < 256; ++j) a += src[j] * T1[(size_t)j * 256 + n];
    weffT[(size_t)n * 768 + k] = f2bf_bits(a);
}

// ---------------- one-pass degree counts for all 4 graphs ----------------

__global__ void count_all(const int* __restrict__ s0, const int* __restrict__ d0,
                          const int* __restrict__ s1, const int* __restrict__ d1,
                          const int* __restrict__ s2, const int* __restrict__ d2,
                          const int* __restrict__ s3, const int* __restrict__ d3,
                          int* __restrict__ cntOut, int* __restrict__ cntIn, int E, int N) {
    int i = blockIdx.x * 256 + threadIdx.x;
    if (i >= E) return;
    atomicAdd(&cntOut[s0[i]], 1);          atomicAdd(&cntIn[d0[i]], 1);
    atomicAdd(&cntOut[N + s1[i]], 1);      atomicAdd(&cntIn[N + d1[i]], 1);
    atomicAdd(&cntOut[2 * N + s2[i]], 1);  atomicAdd(&cntIn[2 * N + d2[i]], 1);
    atomicAdd(&cntOut[3 * N + s3[i]], 1);  atomicAdd(&cntIn[3 * N + d3[i]], 1);
}

// ---------------- CSR scan (4 graphs, 1 block each) + norms fused ----------------

__global__ void scan4norm(const int* __restrict__ cntOut, const int* __restrict__ cntIn,
                          int* __restrict__ rp4, float* __restrict__ norms, int N) {
    __shared__ int partial[1024];
    int g = blockIdx.x;
    const int* counts = cntIn + (size_t)g * N;
    int* rowptr = rp4 + (size_t)g * (N + 1);
    int tid = threadIdx.x;

    int add = (g == 3) ? 1 : 0;
    for (int idx = tid; idx < 2 * N; idx += 1024) {
        int c = (idx < N) ? (cntOut[g * N + idx] + add) : (cntIn[g * N + idx - N] + add);
        norms[(size_t)g * 2 * N + idx] = c > 0 ? rsqrtf((float)c) : 0.0f;
    }

    int per = (N + 1023) >> 10;
    int start = tid * per;
    int s = 0;
    for (int i = 0; i < per; ++i) {
        int idx = start + i;
        if (idx < N) s += counts[idx];
    }
    partial[tid] = s;
    __syncthreads();
    for (int off = 1; off < 1024; off <<= 1) {
        int v = (tid >= off) ? partial[tid - off] : 0;
        __syncthreads();
        partial[tid] += v;
        __syncthreads();
    }
    int run = (tid > 0) ? partial[tid - 1] : 0;
    for (int i = 0; i < per; ++i) {
        int idx = start + i;
        if (idx < N) { rowptr[idx] = run; run += counts[idx]; }
    }
    if (tid == 1023) rowptr[N] = partial[1023];
}

__global__ void scatter4(const int* __restrict__ s0, const int* __restrict__ d0,
                         const int* __restrict__ s1, const int* __restrict__ d1,
                         const int* __restrict__ s2, const int* __restrict__ d2,
                         const int* __restrict__ s3, const int* __restrict__ d3,
                         const int* __restrict__ rp4, int* __restrict__ cursor4,
                         int* __restrict__ col4, int E, int N) {
    int g = blockIdx.y;
    const int* ss[4] = { s0, s1, s2, s3 };
    const int* dd[4] = { d0, d1, d2, d3 };
    int i = blockIdx.x * 256 + threadIdx.x;
    if (i >= E) return;
    int d = dd[g][i];
    int pos = atomicAdd(&cursor4[g * N + d], 1);
    col4[(size_t)g * E + rp4[(size_t)g * (N + 1) + d] + pos] = ss[g][i];
}

// ---------------- bf16 MFMA GEMM (batched via grid.z) ----------------
// POST=0: C = acc*scale + bias ; POST=1: C = (acc + bias)*scale
// BT is B transposed [NC,K]. 128x128 tile, 4 waves, 16x16x32 MFMA, XOR-swizzled LDS.

template<int HAS_SCALE, int HAS_BIAS, int POST>
__global__ __launch_bounds__(256) void gemm_bf16(
    const ushort* __restrict__ A, const ushort* __restrict__ BT,
    const float* __restrict__ rowscale, const float* __restrict__ bias,
    ushort* __restrict__ C, int M, int K, int NC,
    size_t aStride, size_t btStride, size_t cStride, int sStride)
{
    int v = blockIdx.z;
    A += (size_t)v * aStride;
    BT += (size_t)v * btStride;
    C += (size_t)v * cStride;
    if (HAS_SCALE) rowscale += (size_t)v * sStride;

    __shared__ ushort As[128 * 64];
    __shared__ ushort Bs[128 * 64];
    int tid = threadIdx.x;
    int wave = tid >> 6, lane = tid & 63;
    int wr = wave >> 1, wc = wave & 1;
    int rowBase = blockIdx.y * 128, colBase = blockIdx.x * 128;
    int lr = lane & 15, kg = lane >> 4;

    f32x4 acc[4][4] = {};

    for (int k0 = 0; k0 < K; k0 += 64) {
#pragma unroll
        for (int i = 0; i < 4; ++i) {
            int id = i * 256 + tid;
            int row = id >> 3;
            int co  = (id & 7) << 3;
            int boff = ((row * 64 + co) << 1) ^ ((row & 7) << 4);
            int ar = rowBase + row; if (ar >= M) ar = M - 1;
            uint4 av = *(const uint4*)(A + (size_t)ar * K + k0 + co);
            *(uint4*)((char*)As + boff) = av;
            int bc = colBase + row;
            uint4 bv = *(const uint4*)(BT + (size_t)bc * K + k0 + co);
            *(uint4*)((char*)Bs + boff) = bv;
        }
        __syncthreads();
#pragma unroll
        for (int ks = 0; ks < 2; ++ks) {
            s16x8 afr[4], bfr[4];
#pragma unroll
            for (int m = 0; m < 4; ++m) {
                int fr = wr * 64 + m * 16 + lr;
                int boff = ((fr * 64 + ks * 32 + kg * 8) << 1) ^ ((fr & 7) << 4);
                afr[m] = *(const s16x8*)((char*)As + boff);
            }
#pragma unroll
            for (int n = 0; n < 4; ++n) {
                int fc = wc * 64 + n * 16 + lr;
                int boff = ((fc * 64 + ks * 32 + kg * 8) << 1) ^ ((fc & 7) << 4);
                bfr[n] = *(const s16x8*)((char*)Bs + boff);
            }
#pragma unroll
            for (int m = 0; m < 4; ++m)
#pragma unroll
                for (int n = 0; n < 4; ++n)
                    acc[m][n] = __builtin_amdgcn_mfma_f32_16x16x32_bf16(afr[m], bfr[n], acc[m][n], 0, 0, 0);
        }
        __syncthreads();
    }

#pragma unroll
    for (int m = 0; m < 4; ++m) {
#pragma unroll
        for (int i = 0; i < 4; ++i) {
            int r = rowBase + wr * 64 + m * 16 + kg * 4 + i;
            if (r >= M) continue;
            float s = HAS_SCALE ? rowscale[r] : 1.0f;
#pragma unroll
            for (int n = 0; n < 4; ++n) {
                int c = colBase + wc * 64 + n * 16 + lr;
                float vv = acc[m][n][i];
                if (POST) {
                    vv = (vv + (HAS_BIAS ? bias[c] : 0.0f)) * s;
                } else {
                    vv *= s;
                    if (HAS_BIAS) vv += bias[c];
                }
                C[(size_t)r * NC + c] = f2bf_bits(vv);
            }
        }
    }
}

// ---------------- fused gather SpMM (bf16 in, fp32 accum), batched via grid.y ----------------

#define ACC8(u) { acc[0]+=__uint_as_float(u.x<<16); acc[1]+=__uint_as_float(u.x&0xffff0000u); \
                  acc[2]+=__uint_as_float(u.y<<16); acc[3]+=__uint_as_float(u.y&0xffff0000u); \
                  acc[4]+=__uint_as_float(u.z<<16); acc[5]+=__uint_as_float(u.z&0xffff0000u); \
                  acc[6]+=__uint_as_float(u.w<<16); acc[7]+=__uint_as_float(u.w&0xffff0000u); }

template<int W, int RELU, int SELF, int OUTF32>
__global__ __launch_bounds__(256) void spmm_bf16(
    const int* __restrict__ rp4, const int* __restrict__ col4,
    const ushort* __restrict__ hB, const float* __restrict__ normB,
    const float* __restrict__ b0v, const float* __restrict__ b1v, const float* __restrict__ b2v,
    ushort* __restrict__ outB, float* __restrict__ outf,
    int M, int E, size_t hStride, int ninStride, size_t outStride, int ldOut, int colOffPerV)
{
    constexpr int TPR = W / 8;
    constexpr int RPB = 256 / TPR;
    int v = blockIdx.y;
    const int* rowptr = rp4 + (size_t)v * (M + 1);
    const int* col = col4 + (size_t)v * E;
    const ushort* h = hB + (size_t)v * hStride;
    const float* n_in = normB + (size_t)v * ninStride + M;
    const float* bias = (v == 0) ? b0v : (v == 1 ? b1v : b2v);
    ushort* outb = outB + (size_t)v * outStride;
    int cOff = colOffPerV * v;

    int lpr = threadIdx.x & (TPR - 1);
    int r = blockIdx.x * RPB + (threadIdx.x / TPR);
    if (r >= M) return;
    int c = lpr * 8;

    float acc[8] = {};
    int beg = rowptr[r], end = rowptr[r + 1];
    int j = beg;
    for (; j + 7 < end; j += 8) {
        int sA = col[j], sB = col[j + 1], sC = col[j + 2], sD = col[j + 3];
        int sE = col[j + 4], sF = col[j + 5], sG = col[j + 6], sH = col[j + 7];
        uint4 uA = *(const uint4*)(h + (size_t)sA * W + c);
        uint4 uB = *(const uint4*)(h + (size_t)sB * W + c);
        uint4 uC = *(const uint4*)(h + (size_t)sC * W + c);
        uint4 uD = *(const uint4*)(h + (size_t)sD * W + c);
        uint4 uE = *(const uint4*)(h + (size_t)sE * W + c);
        uint4 uF = *(const uint4*)(h + (size_t)sF * W + c);
        uint4 uG = *(const uint4*)(h + (size_t)sG * W + c);
        uint4 uH = *(const uint4*)(h + (size_t)sH * W + c);
        ACC8(uA); ACC8(uB); ACC8(uC); ACC8(uD);
        ACC8(uE); ACC8(uF); ACC8(uG); ACC8(uH);
    }
    for (; j + 3 < end; j += 4) {
        int sA = col[j], sB = col[j + 1], sC = col[j + 2], sD = col[j + 3];
        uint4 uA = *(const uint4*)(h + (size_t)sA * W + c);
        uint4 uB = *(const uint4*)(h + (size_t)sB * W + c);
        uint4 uC = *(const uint4*)(h + (size_t)sC * W + c);
        uint4 uD = *(const uint4*)(h + (size_t)sD * W + c);
        ACC8(uA); ACC8(uB); ACC8(uC); ACC8(uD);
    }
    for (; j < end; ++j) {
        int s = col[j];
        uint4 u = *(const uint4*)(h + (size_t)s * W + c);
        ACC8(u);
    }
    if (SELF) {
        uint4 u = *(const uint4*)(h + (size_t)r * W + c);
        ACC8(u);
    }
    float ni = n_in[r];
    float o[8];
    float4 bb0 = *(const float4*)(bias + c);
    float4 bb1 = *(const float4*)(bias + c + 4);
    o[0] = acc[0] * ni + bb0.x; o[1] = acc[1] * ni + bb0.y;
    o[2] = acc[2] * ni + bb0.z; o[3] = acc[3] * ni + bb0.w;
    o[4] = acc[4] * ni + bb1.x; o[5] = acc[5] * ni + bb1.y;
    o[6] = acc[6] * ni + bb1.z; o[7] = acc[7] * ni + bb1.w;
    if (RELU) {
#pragma unroll
        for (int q = 0; q < 8; ++q) o[q] = fmaxf(o[q], 0.f);
    }
    uint4 ob;
    ob.x = pk2bf(o[0], o[1]); ob.y = pk2bf(o[2], o[3]);
    ob.z = pk2bf(o[4], o[5]); ob.w = pk2bf(o[6], o[7]);
    *(uint4*)(outb + (size_t)r * ldOut + cOff + c) = ob;
    if (OUTF32) {
        *(float4*)(outf + (size_t)r * W + c) = make_float4(o[0], o[1], o[2], o[3]);
        *(float4*)(outf + (size_t)r * W + c + 4) = make_float4(o[4], o[5], o[6], o[7]);
    }
}

// ---------------- decoder: bf16 MFMA, out[r,c] = sigmoid(dot(Z[r],X[c])), K=128 ----------------

__global__ __launch_bounds__(256) void adj_mfma(
    const ushort* __restrict__ Zb, const ushort* __restrict__ Xb,
    float* __restrict__ out, int M)
{
    int wave = threadIdx.x >> 6;
    int lane = threadIdx.x & 63;
    int wr = wave >> 1, wc = wave & 1;
    int rowBase = blockIdx.y * 128 + wr * 64;
    int colBase = blockIdx.x * 128 + wc * 64;
    int lr = lane & 15;
    int kg = lane >> 4;

    f32x4 acc[4][4] = {};

    int ar[4], bc[4];
#pragma unroll
    for (int m = 0; m < 4; ++m) {
        int r = rowBase + m * 16 + lr; ar[m] = (r < M) ? r : (M - 1);
        int c = colBase + m * 16 + lr; bc[m] = (c < M) ? c : (M - 1);
    }

#pragma unroll
    for (int ks = 0; ks < 4; ++ks) {
        s16x8 afr[4], bfr[4];
#pragma unroll
        for (int m = 0; m < 4; ++m)
            afr[m] = *(const s16x8*)(Zb + (size_t)ar[m] * 128 + ks * 32 + kg * 8);
#pragma unroll
        for (int n = 0; n < 4; ++n)
            bfr[n] = *(const s16x8*)(Xb + (size_t)bc[n] * 128 + ks * 32 + kg * 8);
#pragma unroll
        for (int m = 0; m < 4; ++m)
#pragma unroll
            for (int n = 0; n < 4; ++n)
                acc[m][n] = __builtin_amdgcn_mfma_f32_16x16x32_bf16(afr[m], bfr[n], acc[m][n], 0, 0, 0);
    }

#pragma unroll
    for (int m = 0; m < 4; ++m)
#pragma unroll
        for (int n = 0; n < 4; ++n)
#pragma unroll
            for (int i = 0; i < 4; ++i)
                acc[m][n][i] = sigmoidf_fast(acc[m][n][i]);

    size_t NN = (size_t)M * M;
#pragma unroll
    for (int p = 0; p < 3; ++p) {
        float* base = out + (size_t)p * NN;
#pragma unroll
        for (int m = 0; m < 4; ++m) {
#pragma unroll
            for (int i = 0; i < 4; ++i) {
                int r = rowBase + m * 16 + kg * 4 + i;
                if (r >= M) continue;
                float* rowp = base + (size_t)r * M;
#pragma unroll
                for (int n = 0; n < 4; ++n) {
                    int c = colBase + n * 16 + lr;
                    if (c < M) __builtin_nontemporal_store(acc[m][n][i], rowp + c);
                }
            }
        }
    }
}

// ---------------- launcher ----------------

extern "C" void kernel_launch(void* const* d_in, const int* in_sizes, int n_in,
                              void* d_out, int out_size, void* d_ws, size_t ws_size,
                              hipStream_t stream)
{
    const int N = in_sizes[0] / 512;   // 10000
    const int E = in_sizes[3];         // 320000

    const float* feat[3] = { (const float*)d_in[0], (const float*)d_in[1], (const float*)d_in[2] };
    const int* gsrc[4] = { (const int*)d_in[3], (const int*)d_in[5], (const int*)d_in[7], (const int*)d_in[9] };
    const int* gdst[4] = { (const int*)d_in[4], (const int*)d_in[6], (const int*)d_in[8], (const int*)d_in[10] };
    const float* W0[3] = { (const float*)d_in[11], (const float*)d_in[15], (const float*)d_in[19] };
    const float* B0[3] = { (const float*)d_in[12], (const float*)d_in[16], (const float*)d_in[20] };
    const float* W1[3] = { (const float*)d_in[13], (const float*)d_in[17], (const float*)d_in[21] };
    const float* B1[3] = { (const float*)d_in[14], (const float*)d_in[18], (const float*)d_in[22] };
    const float* fw[3] = { (const float*)d_in[23], (const float*)d_in[24], (const float*)d_in[25] };
    const float* fcw = (const float*)d_in[26];
    const float* fcb = (const float*)d_in[27];
    const float* wm0 = (const float*)d_in[28];
    const float* bm0 = (const float*)d_in[29];
    const float* wm1 = (const float*)d_in[30];
    const float* bm1 = (const float*)d_in[31];
    const float* decw = (const float*)d_in[32];
    float* out = (float*)d_out;

    // ---- workspace layout ----
    uint8_t* p = (uint8_t*)d_ws;
    auto alloc = [&](size_t bytes) { void* r = p; p += (bytes + 255) & ~(size_t)255; return r; };

    float*  norms   = (float*)alloc((size_t)8 * N * 4);
    ushort* featb   = (ushort*)alloc((size_t)3 * N * 512 * 2);
    ushort* w0T     = (ushort*)alloc((size_t)3 * 512 * 512 * 2);
    ushort* w1T     = (ushort*)alloc((size_t)3 * 256 * 512 * 2);
    ushort* wm1T    = (ushort*)alloc((size_t)128 * 256 * 2);
    ushort* decT    = (ushort*)alloc((size_t)128 * 128 * 2);
    float*  T1f     = (float*)alloc((size_t)257 * 256 * 4);   // fc@wm0 + bias row
    ushort* weffT   = (ushort*)alloc((size_t)256 * 768 * 2);  // (Fw@fc@wm0)^T
    ushort* h512_3  = (ushort*)alloc((size_t)3 * N * 512 * 2);
    ushort* hb512_3 = (ushort*)alloc((size_t)3 * N * 512 * 2);
    ushort* h256_3  = (ushort*)alloc((size_t)3 * N * 256 * 2);
    ushort* hvcat   = (ushort*)alloc((size_t)N * 768 * 2);
    ushort* m256    = (ushort*)alloc((size_t)N * 256 * 2);
    ushort* xh1     = (ushort*)alloc((size_t)N * 256 * 2);
    ushort* h128    = (ushort*)alloc((size_t)N * 128 * 2);
    ushort* xb      = (ushort*)alloc((size_t)N * 128 * 2);
    ushort* zb      = (ushort*)alloc((size_t)N * 128 * 2);
    int* cntOut     = (int*)alloc((size_t)4 * N * 4);     // must stay contiguous:
    int* cntIn      = (int*)alloc((size_t)4 * N * 4);     //   cntOut | cntIn | cursor4
    int* cursor4    = (int*)alloc((size_t)4 * N * 4);
    int* rp4        = (int*)alloc((size_t)4 * (N + 1) * 4);
    int* col4       = (int*)alloc((size_t)4 * E * 4);

    // ---- fused prep (one launch): zero + tiled transposes + T1 + feature f2bf ----
    PrepArgs pa;
    pa.zeroPtr = (int4*)cntOut; pa.nZero4 = 12 * N / 4;
    int tb = 0;
    int jn = 0;
    auto addJob = [&](const float* s, ushort* d, int K, int NC, int ld) {
        pa.tsrc[jn] = s; pa.tdst[jn] = d; pa.tNC[jn] = NC; pa.tld[jn] = ld;
        pa.tTileBase[jn] = tb; tb += (K >> 5) * (NC >> 5); ++jn;
    };
    for (int v = 0; v < 3; ++v) addJob(W0[v], w0T + (size_t)v * 512 * 512, 512, 512, 512);
    for (int v = 0; v < 3; ++v) addJob(W1[v], w1T + (size_t)v * 256 * 512, 512, 256, 512);
    addJob(wm1, wm1T, 256, 128, 256);
    addJob(decw, decT, 128, 128, 128);
    pa.tTileBase[8] = tb;
    pa.fc = fcw; pa.wm0 = wm0; pa.fcb = fcb; pa.T1 = T1f;
    pa.fsrc[0] = feat[0]; pa.fsrc[1] = feat[1]; pa.fsrc[2] = feat[2];
    pa.fdst = featb; pa.fn4 = N * 512 / 4;
    pa.zBlocks = (pa.nZero4 + 255) / 256;
    pa.tBlocks = tb;
    pa.t1Blocks = 257;
    int fBlocks = 3 * ((pa.fn4 + 255) / 256);
    prep_misc<<<pa.zBlocks + pa.tBlocks + pa.t1Blocks + fBlocks, 256, 0, stream>>>(pa);

    weff_main<<<768, 256, 0, stream>>>(fw[0], fw[1], fw[2], T1f, weffT);

    // ---- graph prep ----
    count_all<<<(E + 255) / 256, 256, 0, stream>>>(
        gsrc[0], gdst[0], gsrc[1], gdst[1], gsrc[2], gdst[2], gsrc[3], gdst[3], cntOut, cntIn, E, N);
    scan4norm<<<4, 1024, 0, stream>>>(cntOut, cntIn, rp4, norms, N);
    scatter4<<<dim3((E + 255) / 256, 4), 256, 0, stream>>>(
        gsrc[0], gdst[0], gsrc[1], gdst[1], gsrc[2], gdst[2], gsrc[3], gdst[3],
        rp4, cursor4, col4, E, N);

    // ---- per-view GCN stacks (batched over 3 views) ----
    gemm_bf16<1, 0, 0><<<dim3(4, (N + 127) / 128, 3), 256, 0, stream>>>(
        featb, w0T, norms, nullptr, h512_3, N, 512, 512,
        (size_t)N * 512, (size_t)512 * 512, (size_t)N * 512, 2 * N);
    spmm_bf16<512, 1, 0, 0><<<dim3((N + 3) / 4, 3), 256, 0, stream>>>(
        rp4, col4, h512_3, norms, B0[0], B0[1], B0[2], hb512_3, nullptr,
        N, E, (size_t)N * 512, 2 * N, (size_t)N * 512, 512, 0);
    gemm_bf16<1, 0, 0><<<dim3(2, (N + 127) / 128, 3), 256, 0, stream>>>(
        hb512_3, w1T, norms, nullptr, h256_3, N, 512, 256,
        (size_t)N * 512, (size_t)256 * 512, (size_t)N * 256, 2 * N);
    spmm_bf16<256, 0, 0, 0><<<dim3((N + 7) / 8, 3), 256, 0, stream>>>(
        rp4, col4, h256_3, norms, B1[0], B1[1], B1[2], hvcat, nullptr,
        N, E, (size_t)N * 256, 2 * N, 0, 768, 256);

    // ---- collapsed fusion + wm0: m256 = (hvcat @ W_eff + b_eff) * n_out ----
    gemm_bf16<1, 1, 1><<<dim3(2, (N + 127) / 128, 1), 256, 0, stream>>>(
        hvcat, weffT, norms + 6 * N, T1f + 256 * 256, m256, N, 768, 256, 0, 0, 0, 0);

    // ---- fusion-graph GCN (graph 3; self loops in epilogue) ----
    const int* rpF = rp4 + 3 * (N + 1);
    const int* colF = col4 + (size_t)3 * E;
    spmm_bf16<256, 1, 1, 0><<<dim3((N + 7) / 8, 1), 256, 0, stream>>>(
        rpF, colF, m256, norms + 6 * N, bm0, bm0, bm0, xh1, nullptr,
        N, E, 0, 0, 0, 256, 0);
    gemm_bf16<1, 0, 0><<<dim3(1, (N + 127) / 128, 1), 256, 0, stream>>>(
        xh1, wm1T, norms + 6 * N, nullptr, h128, N, 256, 128, 0, 0, 0, 0);
    float* xhf = out + (size_t)3 * N * N;
    spmm_bf16<128, 0, 1, 1><<<dim3((N + 15) / 16, 1), 256, 0, stream>>>(
        rpF, colF, h128, norms + 6 * N, bm1, bm1, bm1, xb, xhf,
        N, E, 0, 0, 0, 128, 0);

    // ---- decoder ----
    gemm_bf16<0, 0, 0><<<dim3(1, (N + 127) / 128, 1), 256, 0, stream>>>(
        xb, decT, nullptr, nullptr, zb, N, 128, 128, 0, 0, 0, 0);
    dim3 agrid((N + 127) / 128, (N + 127) / 128);
    adj_mfma<<<agrid, 256, 0, stream>>>(zb, xb, out, N);
}